// Round 1
// baseline (1529.757 us; speedup 1.0000x reference)
//
#include <hip/hip_runtime.h>
#include <hip/hip_bf16.h>
#include <math.h>

// Problem constants (fixed by setup_inputs)
#define Bq 8
#define Nq 2048
#define Pq 64
#define Dq 128
#define Kq 16
#define BNq (Bq * Nq)   // 16384 points total

// ---------------------------------------------------------------------------
// Kernel 1: exact kNN (top-16 by d2 = x2_i + x2_j - 2*dot, stable ties by idx)
// 64 blocks x 256 threads; each block: one batch-chunk of 256 queries,
// full batch point cloud staged in LDS as float4 (x,y,z,|x|^2).
// ---------------------------------------------------------------------------
__global__ __launch_bounds__(256) void knn_kernel(const float* __restrict__ x,
                                                  int* __restrict__ knn) {
    __shared__ float4 sx[Nq];                       // 32 KB
    const int b = blockIdx.x >> 3;
    const int chunk = blockIdx.x & 7;
    const float* xb = x + b * Nq * 3;
    for (int j = threadIdx.x; j < Nq; j += 256) {
        float x0 = xb[j * 3 + 0], x1 = xb[j * 3 + 1], x2 = xb[j * 3 + 2];
        // replicate jnp.sum(x*x): (x0*x0 + x1*x1) + x2*x2, no fma contraction
        float n2 = __fadd_rn(__fadd_rn(__fmul_rn(x0, x0), __fmul_rn(x1, x1)),
                             __fmul_rn(x2, x2));
        sx[j] = make_float4(x0, x1, x2, n2);
    }
    __syncthreads();
    const int i = chunk * 256 + threadIdx.x;
    const float4 q = sx[i];
    float bd[Kq];
    int bj[Kq];
#pragma unroll
    for (int s = 0; s < Kq; ++s) { bd[s] = INFINITY; bj[s] = 0; }
    for (int j = 0; j < Nq; ++j) {
        float4 p = sx[j];
        float dot = __fadd_rn(__fadd_rn(__fmul_rn(q.x, p.x), __fmul_rn(q.y, p.y)),
                              __fmul_rn(q.z, p.z));
        float d = __fsub_rn(__fadd_rn(q.w, p.w), __fmul_rn(2.0f, dot));
        // strict < : equal distances keep the earlier index (stable argsort)
        if (d < bd[Kq - 1]) {
            bd[Kq - 1] = d; bj[Kq - 1] = j;
#pragma unroll
            for (int s = Kq - 1; s >= 1; --s) {
                if (bd[s] < bd[s - 1]) {          // strict: stability preserved
                    float td = bd[s]; bd[s] = bd[s - 1]; bd[s - 1] = td;
                    int tj = bj[s]; bj[s] = bj[s - 1]; bj[s - 1] = tj;
                }
            }
        }
    }
    int* o = knn + (b * Nq + i) * Kq;
#pragma unroll
    for (int s = 0; s < Kq; ++s) o[s] = bj[s];
}

// ---------------------------------------------------------------------------
// Shared matmul tile: out[r][d0..d0+3] += src[r][:] dot W[:, d0..d0+3]
// Block = 256 threads; rg = t>>5 (8 row groups), d0 = (t&31)*4 covers 128 cols.
// W staged in LDS in WROWS-row chunks; src rows read as broadcast float4.
// ---------------------------------------------------------------------------
template <int INNER, int RPT, int WROWS, int SSTR>
__device__ __forceinline__ void mm_tile(const float* __restrict__ Wg,
                                        const float* __restrict__ sSrc,
                                        float* __restrict__ Wbuf,
                                        int rg, int d0, float (&acc)[RPT][4]) {
    constexpr int NST = INNER / WROWS;
    for (int st = 0; st < NST; ++st) {
        __syncthreads();   // protect Wbuf reuse & previous-buffer reads
        for (int idx = threadIdx.x; idx < WROWS * 128; idx += 256)
            Wbuf[idx] = Wg[st * WROWS * 128 + idx];
        __syncthreads();
#pragma unroll
        for (int i4 = 0; i4 < WROWS; i4 += 4) {
            const int i = st * WROWS + i4;
            float4 w0 = *(const float4*)&Wbuf[(i4 + 0) * 128 + d0];
            float4 w1 = *(const float4*)&Wbuf[(i4 + 1) * 128 + d0];
            float4 w2 = *(const float4*)&Wbuf[(i4 + 2) * 128 + d0];
            float4 w3 = *(const float4*)&Wbuf[(i4 + 3) * 128 + d0];
#pragma unroll
            for (int jr = 0; jr < RPT; ++jr) {
                const float4 h = *(const float4*)&sSrc[(rg * RPT + jr) * SSTR + i];
                acc[jr][0] = fmaf(h.x, w0.x, fmaf(h.y, w1.x, fmaf(h.z, w2.x, fmaf(h.w, w3.x, acc[jr][0]))));
                acc[jr][1] = fmaf(h.x, w0.y, fmaf(h.y, w1.y, fmaf(h.z, w2.y, fmaf(h.w, w3.y, acc[jr][1]))));
                acc[jr][2] = fmaf(h.x, w0.z, fmaf(h.y, w1.z, fmaf(h.z, w2.z, fmaf(h.w, w3.z, acc[jr][2]))));
                acc[jr][3] = fmaf(h.x, w0.w, fmaf(h.y, w1.w, fmaf(h.z, w2.w, fmaf(h.w, w3.w, acc[jr][3]))));
            }
        }
    }
}

// ---------------------------------------------------------------------------
// Kernel 2: per-point features.
// f = in_f@Wfc1+b ; psi = f@Wpsi ; alpha = f@Walpha ;
// base = f@Wphi + relu(f@Wdpt1+b)@Wdpt2+b   (phi + dropped, fused)
// 1024 blocks x 256 threads; 16 points per block. LDS ~45 KB.
// ---------------------------------------------------------------------------
__global__ __launch_bounds__(256) void feat_kernel(
    const float* __restrict__ in_f,
    const float* __restrict__ Wfc1, const float* __restrict__ bfc1,
    const float* __restrict__ Wphi, const float* __restrict__ Wpsi,
    const float* __restrict__ Walpha,
    const float* __restrict__ Wdpt1, const float* __restrict__ bdpt1,
    const float* __restrict__ Wdpt2, const float* __restrict__ bdpt2,
    float* __restrict__ base, float* __restrict__ psi, float* __restrict__ alpha) {
    __shared__ __align__(16) float sIn[16 * 68];    // in_f rows (pad 68: f4-aligned)
    __shared__ __align__(16) float sF[16 * 132];    // f
    __shared__ __align__(16) float sT[16 * 132];    // t1 = relu(f@Wdpt1+b)
    __shared__ __align__(16) float sP[16 * 132];    // phi
    __shared__ __align__(16) float Wbuf[32 * 128];  // 16 KB stage
    const int t = threadIdx.x;
    const int p0 = blockIdx.x * 16;
    const int rg = t >> 5;            // 0..7 -> rows rg*2, rg*2+1
    const int d0 = (t & 31) * 4;

    for (int idx = t; idx < 16 * 64; idx += 256) {
        int r = idx >> 6, i = idx & 63;
        sIn[r * 68 + i] = in_f[(p0 + r) * 64 + i];
    }
    // (mm_tile's first __syncthreads orders this store before reads)

    float acc[2][4];
    float4 bb;

    // ---- f = in_f @ Wfc1 + b ----
    bb = *(const float4*)&bfc1[d0];
#pragma unroll
    for (int jr = 0; jr < 2; ++jr) { acc[jr][0] = bb.x; acc[jr][1] = bb.y; acc[jr][2] = bb.z; acc[jr][3] = bb.w; }
    mm_tile<64, 2, 32, 68>(Wfc1, sIn, Wbuf, rg, d0, acc);
    __syncthreads();
#pragma unroll
    for (int jr = 0; jr < 2; ++jr)
        *(float4*)&sF[(rg * 2 + jr) * 132 + d0] = make_float4(acc[jr][0], acc[jr][1], acc[jr][2], acc[jr][3]);

    // ---- phi = f @ Wphi (keep in LDS) ----
#pragma unroll
    for (int jr = 0; jr < 2; ++jr) { acc[jr][0] = 0; acc[jr][1] = 0; acc[jr][2] = 0; acc[jr][3] = 0; }
    mm_tile<128, 2, 32, 132>(Wphi, sF, Wbuf, rg, d0, acc);
    __syncthreads();
#pragma unroll
    for (int jr = 0; jr < 2; ++jr)
        *(float4*)&sP[(rg * 2 + jr) * 132 + d0] = make_float4(acc[jr][0], acc[jr][1], acc[jr][2], acc[jr][3]);

    // ---- psi = f @ Wpsi -> global ----
#pragma unroll
    for (int jr = 0; jr < 2; ++jr) { acc[jr][0] = 0; acc[jr][1] = 0; acc[jr][2] = 0; acc[jr][3] = 0; }
    mm_tile<128, 2, 32, 132>(Wpsi, sF, Wbuf, rg, d0, acc);
#pragma unroll
    for (int jr = 0; jr < 2; ++jr)
        *(float4*)&psi[(p0 + rg * 2 + jr) * 128 + d0] = make_float4(acc[jr][0], acc[jr][1], acc[jr][2], acc[jr][3]);

    // ---- alpha = f @ Walpha -> global ----
#pragma unroll
    for (int jr = 0; jr < 2; ++jr) { acc[jr][0] = 0; acc[jr][1] = 0; acc[jr][2] = 0; acc[jr][3] = 0; }
    mm_tile<128, 2, 32, 132>(Walpha, sF, Wbuf, rg, d0, acc);
#pragma unroll
    for (int jr = 0; jr < 2; ++jr)
        *(float4*)&alpha[(p0 + rg * 2 + jr) * 128 + d0] = make_float4(acc[jr][0], acc[jr][1], acc[jr][2], acc[jr][3]);

    // ---- t1 = relu(f @ Wdpt1 + b) ----
    bb = *(const float4*)&bdpt1[d0];
#pragma unroll
    for (int jr = 0; jr < 2; ++jr) { acc[jr][0] = bb.x; acc[jr][1] = bb.y; acc[jr][2] = bb.z; acc[jr][3] = bb.w; }
    mm_tile<128, 2, 32, 132>(Wdpt1, sF, Wbuf, rg, d0, acc);
    __syncthreads();
#pragma unroll
    for (int jr = 0; jr < 2; ++jr)
        *(float4*)&sT[(rg * 2 + jr) * 132 + d0] =
            make_float4(fmaxf(acc[jr][0], 0.f), fmaxf(acc[jr][1], 0.f), fmaxf(acc[jr][2], 0.f), fmaxf(acc[jr][3], 0.f));

    // ---- base = phi + t1 @ Wdpt2 + b -> global ----
    bb = *(const float4*)&bdpt2[d0];
#pragma unroll
    for (int jr = 0; jr < 2; ++jr) { acc[jr][0] = bb.x; acc[jr][1] = bb.y; acc[jr][2] = bb.z; acc[jr][3] = bb.w; }
    mm_tile<128, 2, 32, 132>(Wdpt2, sT, Wbuf, rg, d0, acc);
#pragma unroll
    for (int jr = 0; jr < 2; ++jr) {
        int r = rg * 2 + jr;
        float4 ph = *(const float4*)&sP[r * 132 + d0];
        *(float4*)&base[(p0 + r) * 128 + d0] =
            make_float4(acc[jr][0] + ph.x, acc[jr][1] + ph.y, acc[jr][2] + ph.z, acc[jr][3] + ph.w);
    }
}

// ---------------------------------------------------------------------------
// Kernel 3: per-(point, neighbor) pipeline. 8192 blocks x 256 threads,
// 2 points (= 32 rows of K=16) per block. LDS ~59 KB -> 2 blocks/CU.
//   h1 = relu(diff@Wdel1+b); delta = h1@Wdel2+b;
//   pre = base[n] - psi[j] + delta; g1 = relu(pre@Wgam1+b);
//   gamma = g1@Wgam2+b; rho = softmax_k(gamma/4);
//   y = sum_k rho*(alpha[j]+delta); out = y@Wfc2 + b + in_f
// ---------------------------------------------------------------------------
__global__ __launch_bounds__(256) void main_kernel(
    const float* __restrict__ x, const float* __restrict__ in_f,
    const float* __restrict__ Wdel1, const float* __restrict__ bdel1,
    const float* __restrict__ Wdel2, const float* __restrict__ bdel2,
    const float* __restrict__ Wgam1, const float* __restrict__ bgam1,
    const float* __restrict__ Wgam2, const float* __restrict__ bgam2,
    const float* __restrict__ Wfc2, const float* __restrict__ bfc2,
    const float* __restrict__ base, const float* __restrict__ psi,
    const float* __restrict__ alpha, const int* __restrict__ knn,
    float* __restrict__ out) {
    __shared__ __align__(16) float sH[32 * 132];    // h1, 16.9 KB
    __shared__ __align__(16) float sD[32 * 132];    // delta
    __shared__ __align__(16) float sP[32 * 132];    // pre -> g1 -> gamma (in place)
    __shared__ __align__(16) float Wbuf[16 * 128];  // 8 KB stage
    __shared__ float sDiff[32][4];
    __shared__ int sIdx[32];
    __shared__ float sY[2][128];
    const int t = threadIdx.x;
    const int p0 = blockIdx.x * 2;                  // global point id base
    const int b = p0 >> 11;                         // / 2048
    const int rg = t >> 5;                          // 0..7 -> rows rg*4..rg*4+3
    const int d0 = (t & 31) * 4;

    if (t < 32) {
        int p = p0 + (t >> 4);
        int kk = t & 15;
        int j = knn[p * Kq + kk];
        sIdx[t] = b * Nq + j;                       // global neighbor row
        const float* xq = x + p * 3;
        const float* xn = x + (b * Nq + j) * 3;
        sDiff[t][0] = xq[0] - xn[0];
        sDiff[t][1] = xq[1] - xn[1];
        sDiff[t][2] = xq[2] - xn[2];
    }
    __syncthreads();

    // ---- h1 = relu(diff @ Wdel1 + b) ----
    {
        float4 w0 = *(const float4*)&Wdel1[0 * 128 + d0];
        float4 w1 = *(const float4*)&Wdel1[1 * 128 + d0];
        float4 w2 = *(const float4*)&Wdel1[2 * 128 + d0];
        float4 bbd = *(const float4*)&bdel1[d0];
#pragma unroll
        for (int jr = 0; jr < 4; ++jr) {
            int r = rg * 4 + jr;
            float dx = sDiff[r][0], dy = sDiff[r][1], dz = sDiff[r][2];
            float4 h;
            h.x = fmaxf(fmaf(dz, w2.x, fmaf(dy, w1.x, fmaf(dx, w0.x, bbd.x))), 0.f);
            h.y = fmaxf(fmaf(dz, w2.y, fmaf(dy, w1.y, fmaf(dx, w0.y, bbd.y))), 0.f);
            h.z = fmaxf(fmaf(dz, w2.z, fmaf(dy, w1.z, fmaf(dx, w0.z, bbd.z))), 0.f);
            h.w = fmaxf(fmaf(dz, w2.w, fmaf(dy, w1.w, fmaf(dx, w0.w, bbd.w))), 0.f);
            *(float4*)&sH[r * 132 + d0] = h;
        }
    }

    float acc[4][4];
    float4 bb;

    // ---- delta = h1 @ Wdel2 + b ; pre = delta + base - psi ----
    bb = *(const float4*)&bdel2[d0];
#pragma unroll
    for (int jr = 0; jr < 4; ++jr) { acc[jr][0] = bb.x; acc[jr][1] = bb.y; acc[jr][2] = bb.z; acc[jr][3] = bb.w; }
    mm_tile<128, 4, 16, 132>(Wdel2, sH, Wbuf, rg, d0, acc);
    {
        const int p = p0 + (rg >> 2);
        float4 bas = *(const float4*)&base[p * 128 + d0];
        __syncthreads();   // all reads of sH done before anything else proceeds
#pragma unroll
        for (int jr = 0; jr < 4; ++jr) {
            int r = rg * 4 + jr;
            float4 ps = *(const float4*)&psi[sIdx[r] * 128 + d0];
            *(float4*)&sD[r * 132 + d0] = make_float4(acc[jr][0], acc[jr][1], acc[jr][2], acc[jr][3]);
            *(float4*)&sP[r * 132 + d0] = make_float4(acc[jr][0] + bas.x - ps.x, acc[jr][1] + bas.y - ps.y,
                                                      acc[jr][2] + bas.z - ps.z, acc[jr][3] + bas.w - ps.w);
        }
    }

    // ---- g1 = relu(pre @ Wgam1 + b) (in place into sP) ----
    bb = *(const float4*)&bgam1[d0];
#pragma unroll
    for (int jr = 0; jr < 4; ++jr) { acc[jr][0] = bb.x; acc[jr][1] = bb.y; acc[jr][2] = bb.z; acc[jr][3] = bb.w; }
    mm_tile<128, 4, 16, 132>(Wgam1, sP, Wbuf, rg, d0, acc);
    __syncthreads();       // all reads of pre complete before overwrite
#pragma unroll
    for (int jr = 0; jr < 4; ++jr)
        *(float4*)&sP[(rg * 4 + jr) * 132 + d0] =
            make_float4(fmaxf(acc[jr][0], 0.f), fmaxf(acc[jr][1], 0.f), fmaxf(acc[jr][2], 0.f), fmaxf(acc[jr][3], 0.f));

    // ---- gamma = g1 @ Wgam2 + b (in place into sP) ----
    bb = *(const float4*)&bgam2[d0];
#pragma unroll
    for (int jr = 0; jr < 4; ++jr) { acc[jr][0] = bb.x; acc[jr][1] = bb.y; acc[jr][2] = bb.z; acc[jr][3] = bb.w; }
    mm_tile<128, 4, 16, 132>(Wgam2, sP, Wbuf, rg, d0, acc);
    __syncthreads();
#pragma unroll
    for (int jr = 0; jr < 4; ++jr)
        *(float4*)&sP[(rg * 4 + jr) * 132 + d0] = make_float4(acc[jr][0], acc[jr][1], acc[jr][2], acc[jr][3]);
    __syncthreads();

    // ---- softmax over k (per channel) and y = sum_k rho*(alpha+delta) ----
    {
        const int pp = t >> 7;          // point within block
        const int d = t & 127;
        float e[Kq];
        float m = -INFINITY;
#pragma unroll
        for (int kk = 0; kk < Kq; ++kk) m = fmaxf(m, sP[(pp * 16 + kk) * 132 + d]);
        m *= 0.25f;                     // exact (pow2 scale)
        float sum = 0.f;
#pragma unroll
        for (int kk = 0; kk < Kq; ++kk) {
            float ev = expf(0.25f * sP[(pp * 16 + kk) * 132 + d] - m);
            e[kk] = ev;
            sum += ev;
        }
        float rs = 1.0f / sum;
        float y = 0.f;
#pragma unroll
        for (int kk = 0; kk < Kq; ++kk) {
            int r = pp * 16 + kk;
            float a = alpha[sIdx[r] * 128 + d];
            y = fmaf(e[kk], a + sD[r * 132 + d], y);
        }
        sY[pp][d] = y * rs;
    }
    __syncthreads();

    // ---- out = y @ Wfc2 + b + in_f ----
    if (t < 128) {
        const int pp = t >> 6;
        const int q = t & 63;
        const int p = p0 + pp;
        float a = bfc2[q] + in_f[p * 64 + q];
#pragma unroll 8
        for (int d = 0; d < 128; ++d)
            a = fmaf(sY[pp][d], Wfc2[d * 64 + q], a);
        out[p * 64 + q] = a;
    }
}

// ---------------------------------------------------------------------------
extern "C" void kernel_launch(void* const* d_in, const int* in_sizes, int n_in,
                              void* d_out, int out_size, void* d_ws, size_t ws_size,
                              hipStream_t stream) {
    const float* x     = (const float*)d_in[0];
    const float* in_f  = (const float*)d_in[1];
    const float* Wfc1  = (const float*)d_in[2];
    const float* bfc1  = (const float*)d_in[3];
    const float* Wphi  = (const float*)d_in[4];
    const float* Wpsi  = (const float*)d_in[5];
    const float* Walpha= (const float*)d_in[6];
    const float* Wdpt1 = (const float*)d_in[7];
    const float* bdpt1 = (const float*)d_in[8];
    const float* Wdpt2 = (const float*)d_in[9];
    const float* bdpt2 = (const float*)d_in[10];
    const float* Wgam1 = (const float*)d_in[11];
    const float* bgam1 = (const float*)d_in[12];
    const float* Wgam2 = (const float*)d_in[13];
    const float* bgam2 = (const float*)d_in[14];
    const float* Wdel1 = (const float*)d_in[15];
    const float* bdel1 = (const float*)d_in[16];
    const float* Wdel2 = (const float*)d_in[17];
    const float* bdel2 = (const float*)d_in[18];
    const float* Wfc2  = (const float*)d_in[19];
    const float* bfc2  = (const float*)d_in[20];
    float* out = (float*)d_out;

    // workspace layout (fp32): base | psi | alpha | knn(int)  = ~25 MB
    float* base  = (float*)d_ws;
    float* psi   = base + (size_t)BNq * Dq;
    float* alpha = psi + (size_t)BNq * Dq;
    int*   knn   = (int*)(alpha + (size_t)BNq * Dq);

    knn_kernel<<<64, 256, 0, stream>>>(x, knn);
    feat_kernel<<<BNq / 16, 256, 0, stream>>>(in_f, Wfc1, bfc1, Wphi, Wpsi, Walpha,
                                              Wdpt1, bdpt1, Wdpt2, bdpt2,
                                              base, psi, alpha);
    main_kernel<<<BNq / 2, 256, 0, stream>>>(x, in_f, Wdel1, bdel1, Wdel2, bdel2,
                                             Wgam1, bgam1, Wgam2, bgam2, Wfc2, bfc2,
                                             base, psi, alpha, knn, out);
}

// Round 2
// 766.800 us; speedup vs baseline: 1.9950x; 1.9950x over previous
//
#include <hip/hip_runtime.h>
#include <hip/hip_bf16.h>
#include <math.h>

// Problem constants (fixed by setup_inputs)
#define Bq 8
#define Nq 2048
#define Pq 64
#define Dq 128
#define Kq 16
#define BNq (Bq * Nq)   // 16384 points total

// ---------------------------------------------------------------------------
// Kernel 1: exact kNN (top-16 by d2 = x2_i + x2_j - 2*dot, stable ties).
// v2: 512 blocks x 256 threads. Block = 32 queries x 8 candidate-chunks.
// Each thread: top-16 (insertion sort, registers) over a contiguous 256-
// candidate chunk; then per-query stable lexicographic 8-way merge.
// Chunked-select + (d,idx)-lex merge == stable global argsort top-16.
// ---------------------------------------------------------------------------
__global__ __launch_bounds__(256) void knn_kernel(const float* __restrict__ x,
                                                  int* __restrict__ knn) {
    __shared__ float4 sx[Nq];                       // 32 KB
    __shared__ float sLd[32][8][17];                // +1 pad: de-conflict writes
    __shared__ int   sLi[32][8][17];
    const int b = blockIdx.x >> 6;                  // 64 blocks per batch
    const int q0 = (blockIdx.x & 63) * 32;
    const float* xb = x + b * Nq * 3;
    for (int j = threadIdx.x; j < Nq; j += 256) {
        float x0 = xb[j * 3 + 0], x1 = xb[j * 3 + 1], x2 = xb[j * 3 + 2];
        // replicate jnp.sum(x*x): (x0*x0 + x1*x1) + x2*x2, no fma contraction
        float n2 = __fadd_rn(__fadd_rn(__fmul_rn(x0, x0), __fmul_rn(x1, x1)),
                             __fmul_rn(x2, x2));
        sx[j] = make_float4(x0, x1, x2, n2);
    }
    __syncthreads();
    const int q = threadIdx.x & 31;                 // local query
    const int sub = threadIdx.x >> 5;               // candidate chunk 0..7
    const float4 qv = sx[q0 + q];
    float bd[Kq];
    int bj[Kq];
#pragma unroll
    for (int s = 0; s < Kq; ++s) { bd[s] = INFINITY; bj[s] = 0; }
    const int j0 = sub * 256;
    for (int i = 0; i < 256; ++i) {
        const int j = j0 + i;
        float4 p = sx[j];
        float dot = __fadd_rn(__fadd_rn(__fmul_rn(qv.x, p.x), __fmul_rn(qv.y, p.y)),
                              __fmul_rn(qv.z, p.z));
        float d = __fsub_rn(__fadd_rn(qv.w, p.w), __fmul_rn(2.0f, dot));
        // strict < : equal distances keep the earlier index (stable)
        if (d < bd[Kq - 1]) {
            bd[Kq - 1] = d; bj[Kq - 1] = j;
#pragma unroll
            for (int s = Kq - 1; s >= 1; --s) {
                if (bd[s] < bd[s - 1]) {
                    float td = bd[s]; bd[s] = bd[s - 1]; bd[s - 1] = td;
                    int tj = bj[s]; bj[s] = bj[s - 1]; bj[s - 1] = tj;
                }
            }
        }
    }
#pragma unroll
    for (int s = 0; s < Kq; ++s) { sLd[q][sub][s] = bd[s]; sLi[q][sub][s] = bj[s]; }
    __syncthreads();
    // ---- stable 8-way merge (one thread per query) ----
    if (threadIdx.x < 32) {
        const int mq = threadIdx.x;
        int pos[8]; float hd[8]; int hi[8];
#pragma unroll
        for (int s = 0; s < 8; ++s) {
            pos[s] = 1; hd[s] = sLd[mq][s][0]; hi[s] = sLi[mq][s][0];
        }
        int* o = knn + (b * Nq + q0 + mq) * Kq;
#pragma unroll
        for (int oi = 0; oi < Kq; ++oi) {
            float bdv = hd[0]; int biv = hi[0]; int bs = 0;
#pragma unroll
            for (int s = 1; s < 8; ++s) {
                bool take = (hd[s] < bdv) || (hd[s] == bdv && hi[s] < biv);
                if (take) { bdv = hd[s]; biv = hi[s]; bs = s; }
            }
            o[oi] = biv;
#pragma unroll
            for (int s = 0; s < 8; ++s) {           // static-index update (rule #20)
                if (s == bs) {
                    int pp = pos[s] < Kq ? pos[s] : (Kq - 1);   // clamp addr
                    bool ok = pos[s] < Kq;
                    hd[s] = ok ? sLd[mq][s][pp] : INFINITY;
                    hi[s] = ok ? sLi[mq][s][pp] : 0x7fffffff;
                    pos[s]++;
                }
            }
        }
    }
}

// ---------------------------------------------------------------------------
// Shared matmul tile: out[r][d0..d0+3] += src[r][:] dot W[:, d0..d0+3]
// Block = 256 threads; rg = t>>5 (8 row groups), d0 = (t&31)*4 covers 128 cols.
// W staged in LDS in WROWS-row chunks; src rows read as broadcast float4.
// ---------------------------------------------------------------------------
template <int INNER, int RPT, int WROWS, int SSTR>
__device__ __forceinline__ void mm_tile(const float* __restrict__ Wg,
                                        const float* __restrict__ sSrc,
                                        float* __restrict__ Wbuf,
                                        int rg, int d0, float (&acc)[RPT][4]) {
    constexpr int NST = INNER / WROWS;
    for (int st = 0; st < NST; ++st) {
        __syncthreads();   // protect Wbuf reuse & previous-buffer reads
        for (int idx = threadIdx.x; idx < WROWS * 128; idx += 256)
            Wbuf[idx] = Wg[st * WROWS * 128 + idx];
        __syncthreads();
#pragma unroll
        for (int i4 = 0; i4 < WROWS; i4 += 4) {
            const int i = st * WROWS + i4;
            float4 w0 = *(const float4*)&Wbuf[(i4 + 0) * 128 + d0];
            float4 w1 = *(const float4*)&Wbuf[(i4 + 1) * 128 + d0];
            float4 w2 = *(const float4*)&Wbuf[(i4 + 2) * 128 + d0];
            float4 w3 = *(const float4*)&Wbuf[(i4 + 3) * 128 + d0];
#pragma unroll
            for (int jr = 0; jr < RPT; ++jr) {
                const float4 h = *(const float4*)&sSrc[(rg * RPT + jr) * SSTR + i];
                acc[jr][0] = fmaf(h.x, w0.x, fmaf(h.y, w1.x, fmaf(h.z, w2.x, fmaf(h.w, w3.x, acc[jr][0]))));
                acc[jr][1] = fmaf(h.x, w0.y, fmaf(h.y, w1.y, fmaf(h.z, w2.y, fmaf(h.w, w3.y, acc[jr][1]))));
                acc[jr][2] = fmaf(h.x, w0.z, fmaf(h.y, w1.z, fmaf(h.z, w2.z, fmaf(h.w, w3.z, acc[jr][2]))));
                acc[jr][3] = fmaf(h.x, w0.w, fmaf(h.y, w1.w, fmaf(h.z, w2.w, fmaf(h.w, w3.w, acc[jr][3]))));
            }
        }
    }
}

// ---------------------------------------------------------------------------
// Kernel 2: per-point features.
// f = in_f@Wfc1+b ; psi = f@Wpsi ; alpha = f@Walpha ;
// base = f@Wphi + relu(f@Wdpt1+b)@Wdpt2+b   (phi + dropped, fused)
// 1024 blocks x 256 threads; 16 points per block. LDS ~45 KB.
// ---------------------------------------------------------------------------
__global__ __launch_bounds__(256) void feat_kernel(
    const float* __restrict__ in_f,
    const float* __restrict__ Wfc1, const float* __restrict__ bfc1,
    const float* __restrict__ Wphi, const float* __restrict__ Wpsi,
    const float* __restrict__ Walpha,
    const float* __restrict__ Wdpt1, const float* __restrict__ bdpt1,
    const float* __restrict__ Wdpt2, const float* __restrict__ bdpt2,
    float* __restrict__ base, float* __restrict__ psi, float* __restrict__ alpha) {
    __shared__ __align__(16) float sIn[16 * 68];    // in_f rows (pad 68: f4-aligned)
    __shared__ __align__(16) float sF[16 * 132];    // f
    __shared__ __align__(16) float sT[16 * 132];    // t1 = relu(f@Wdpt1+b)
    __shared__ __align__(16) float sP[16 * 132];    // phi
    __shared__ __align__(16) float Wbuf[32 * 128];  // 16 KB stage
    const int t = threadIdx.x;
    const int p0 = blockIdx.x * 16;
    const int rg = t >> 5;            // 0..7 -> rows rg*2, rg*2+1
    const int d0 = (t & 31) * 4;

    for (int idx = t; idx < 16 * 64; idx += 256) {
        int r = idx >> 6, i = idx & 63;
        sIn[r * 68 + i] = in_f[(p0 + r) * 64 + i];
    }
    // (mm_tile's first __syncthreads orders this store before reads)

    float acc[2][4];
    float4 bb;

    // ---- f = in_f @ Wfc1 + b ----
    bb = *(const float4*)&bfc1[d0];
#pragma unroll
    for (int jr = 0; jr < 2; ++jr) { acc[jr][0] = bb.x; acc[jr][1] = bb.y; acc[jr][2] = bb.z; acc[jr][3] = bb.w; }
    mm_tile<64, 2, 32, 68>(Wfc1, sIn, Wbuf, rg, d0, acc);
    __syncthreads();
#pragma unroll
    for (int jr = 0; jr < 2; ++jr)
        *(float4*)&sF[(rg * 2 + jr) * 132 + d0] = make_float4(acc[jr][0], acc[jr][1], acc[jr][2], acc[jr][3]);

    // ---- phi = f @ Wphi (keep in LDS) ----
#pragma unroll
    for (int jr = 0; jr < 2; ++jr) { acc[jr][0] = 0; acc[jr][1] = 0; acc[jr][2] = 0; acc[jr][3] = 0; }
    mm_tile<128, 2, 32, 132>(Wphi, sF, Wbuf, rg, d0, acc);
    __syncthreads();
#pragma unroll
    for (int jr = 0; jr < 2; ++jr)
        *(float4*)&sP[(rg * 2 + jr) * 132 + d0] = make_float4(acc[jr][0], acc[jr][1], acc[jr][2], acc[jr][3]);

    // ---- psi = f @ Wpsi -> global ----
#pragma unroll
    for (int jr = 0; jr < 2; ++jr) { acc[jr][0] = 0; acc[jr][1] = 0; acc[jr][2] = 0; acc[jr][3] = 0; }
    mm_tile<128, 2, 32, 132>(Wpsi, sF, Wbuf, rg, d0, acc);
#pragma unroll
    for (int jr = 0; jr < 2; ++jr)
        *(float4*)&psi[(p0 + rg * 2 + jr) * 128 + d0] = make_float4(acc[jr][0], acc[jr][1], acc[jr][2], acc[jr][3]);

    // ---- alpha = f @ Walpha -> global ----
#pragma unroll
    for (int jr = 0; jr < 2; ++jr) { acc[jr][0] = 0; acc[jr][1] = 0; acc[jr][2] = 0; acc[jr][3] = 0; }
    mm_tile<128, 2, 32, 132>(Walpha, sF, Wbuf, rg, d0, acc);
#pragma unroll
    for (int jr = 0; jr < 2; ++jr)
        *(float4*)&alpha[(p0 + rg * 2 + jr) * 128 + d0] = make_float4(acc[jr][0], acc[jr][1], acc[jr][2], acc[jr][3]);

    // ---- t1 = relu(f @ Wdpt1 + b) ----
    bb = *(const float4*)&bdpt1[d0];
#pragma unroll
    for (int jr = 0; jr < 2; ++jr) { acc[jr][0] = bb.x; acc[jr][1] = bb.y; acc[jr][2] = bb.z; acc[jr][3] = bb.w; }
    mm_tile<128, 2, 32, 132>(Wdpt1, sF, Wbuf, rg, d0, acc);
    __syncthreads();
#pragma unroll
    for (int jr = 0; jr < 2; ++jr)
        *(float4*)&sT[(rg * 2 + jr) * 132 + d0] =
            make_float4(fmaxf(acc[jr][0], 0.f), fmaxf(acc[jr][1], 0.f), fmaxf(acc[jr][2], 0.f), fmaxf(acc[jr][3], 0.f));

    // ---- base = phi + t1 @ Wdpt2 + b -> global ----
    bb = *(const float4*)&bdpt2[d0];
#pragma unroll
    for (int jr = 0; jr < 2; ++jr) { acc[jr][0] = bb.x; acc[jr][1] = bb.y; acc[jr][2] = bb.z; acc[jr][3] = bb.w; }
    mm_tile<128, 2, 32, 132>(Wdpt2, sT, Wbuf, rg, d0, acc);
#pragma unroll
    for (int jr = 0; jr < 2; ++jr) {
        int r = rg * 2 + jr;
        float4 ph = *(const float4*)&sP[r * 132 + d0];
        *(float4*)&base[(p0 + r) * 128 + d0] =
            make_float4(acc[jr][0] + ph.x, acc[jr][1] + ph.y, acc[jr][2] + ph.z, acc[jr][3] + ph.w);
    }
}

// ---------------------------------------------------------------------------
// Kernel 3: per-(point, neighbor) pipeline. 8192 blocks x 256 threads,
// 2 points (= 32 rows of K=16) per block. LDS ~59 KB -> 2 blocks/CU.
//   h1 = relu(diff@Wdel1+b); delta = h1@Wdel2+b;
//   pre = base[n] - psi[j] + delta; g1 = relu(pre@Wgam1+b);
//   gamma = g1@Wgam2+b; rho = softmax_k(gamma/4);
//   y = sum_k rho*(alpha[j]+delta); out = y@Wfc2 + b + in_f
// ---------------------------------------------------------------------------
__global__ __launch_bounds__(256) void main_kernel(
    const float* __restrict__ x, const float* __restrict__ in_f,
    const float* __restrict__ Wdel1, const float* __restrict__ bdel1,
    const float* __restrict__ Wdel2, const float* __restrict__ bdel2,
    const float* __restrict__ Wgam1, const float* __restrict__ bgam1,
    const float* __restrict__ Wgam2, const float* __restrict__ bgam2,
    const float* __restrict__ Wfc2, const float* __restrict__ bfc2,
    const float* __restrict__ base, const float* __restrict__ psi,
    const float* __restrict__ alpha, const int* __restrict__ knn,
    float* __restrict__ out) {
    __shared__ __align__(16) float sH[32 * 132];    // h1, 16.9 KB
    __shared__ __align__(16) float sD[32 * 132];    // delta
    __shared__ __align__(16) float sP[32 * 132];    // pre -> g1 -> gamma (in place)
    __shared__ __align__(16) float Wbuf[16 * 128];  // 8 KB stage
    __shared__ float sDiff[32][4];
    __shared__ int sIdx[32];
    __shared__ float sY[2][128];
    const int t = threadIdx.x;
    const int p0 = blockIdx.x * 2;                  // global point id base
    const int b = p0 >> 11;                         // / 2048
    const int rg = t >> 5;                          // 0..7 -> rows rg*4..rg*4+3
    const int d0 = (t & 31) * 4;

    if (t < 32) {
        int p = p0 + (t >> 4);
        int kk = t & 15;
        int j = knn[p * Kq + kk];
        sIdx[t] = b * Nq + j;                       // global neighbor row
        const float* xq = x + p * 3;
        const float* xn = x + (b * Nq + j) * 3;
        sDiff[t][0] = xq[0] - xn[0];
        sDiff[t][1] = xq[1] - xn[1];
        sDiff[t][2] = xq[2] - xn[2];
    }
    __syncthreads();

    // ---- h1 = relu(diff @ Wdel1 + b) ----
    {
        float4 w0 = *(const float4*)&Wdel1[0 * 128 + d0];
        float4 w1 = *(const float4*)&Wdel1[1 * 128 + d0];
        float4 w2 = *(const float4*)&Wdel1[2 * 128 + d0];
        float4 bbd = *(const float4*)&bdel1[d0];
#pragma unroll
        for (int jr = 0; jr < 4; ++jr) {
            int r = rg * 4 + jr;
            float dx = sDiff[r][0], dy = sDiff[r][1], dz = sDiff[r][2];
            float4 h;
            h.x = fmaxf(fmaf(dz, w2.x, fmaf(dy, w1.x, fmaf(dx, w0.x, bbd.x))), 0.f);
            h.y = fmaxf(fmaf(dz, w2.y, fmaf(dy, w1.y, fmaf(dx, w0.y, bbd.y))), 0.f);
            h.z = fmaxf(fmaf(dz, w2.z, fmaf(dy, w1.z, fmaf(dx, w0.z, bbd.z))), 0.f);
            h.w = fmaxf(fmaf(dz, w2.w, fmaf(dy, w1.w, fmaf(dx, w0.w, bbd.w))), 0.f);
            *(float4*)&sH[r * 132 + d0] = h;
        }
    }

    float acc[4][4];
    float4 bb;

    // ---- delta = h1 @ Wdel2 + b ; pre = delta + base - psi ----
    bb = *(const float4*)&bdel2[d0];
#pragma unroll
    for (int jr = 0; jr < 4; ++jr) { acc[jr][0] = bb.x; acc[jr][1] = bb.y; acc[jr][2] = bb.z; acc[jr][3] = bb.w; }
    mm_tile<128, 4, 16, 132>(Wdel2, sH, Wbuf, rg, d0, acc);
    {
        const int p = p0 + (rg >> 2);
        float4 bas = *(const float4*)&base[p * 128 + d0];
        __syncthreads();   // all reads of sH done before anything else proceeds
#pragma unroll
        for (int jr = 0; jr < 4; ++jr) {
            int r = rg * 4 + jr;
            float4 ps = *(const float4*)&psi[sIdx[r] * 128 + d0];
            *(float4*)&sD[r * 132 + d0] = make_float4(acc[jr][0], acc[jr][1], acc[jr][2], acc[jr][3]);
            *(float4*)&sP[r * 132 + d0] = make_float4(acc[jr][0] + bas.x - ps.x, acc[jr][1] + bas.y - ps.y,
                                                      acc[jr][2] + bas.z - ps.z, acc[jr][3] + bas.w - ps.w);
        }
    }

    // ---- g1 = relu(pre @ Wgam1 + b) (in place into sP) ----
    bb = *(const float4*)&bgam1[d0];
#pragma unroll
    for (int jr = 0; jr < 4; ++jr) { acc[jr][0] = bb.x; acc[jr][1] = bb.y; acc[jr][2] = bb.z; acc[jr][3] = bb.w; }
    mm_tile<128, 4, 16, 132>(Wgam1, sP, Wbuf, rg, d0, acc);
    __syncthreads();       // all reads of pre complete before overwrite
#pragma unroll
    for (int jr = 0; jr < 4; ++jr)
        *(float4*)&sP[(rg * 4 + jr) * 132 + d0] =
            make_float4(fmaxf(acc[jr][0], 0.f), fmaxf(acc[jr][1], 0.f), fmaxf(acc[jr][2], 0.f), fmaxf(acc[jr][3], 0.f));

    // ---- gamma = g1 @ Wgam2 + b (in place into sP) ----
    bb = *(const float4*)&bgam2[d0];
#pragma unroll
    for (int jr = 0; jr < 4; ++jr) { acc[jr][0] = bb.x; acc[jr][1] = bb.y; acc[jr][2] = bb.z; acc[jr][3] = bb.w; }
    mm_tile<128, 4, 16, 132>(Wgam2, sP, Wbuf, rg, d0, acc);
    __syncthreads();
#pragma unroll
    for (int jr = 0; jr < 4; ++jr)
        *(float4*)&sP[(rg * 4 + jr) * 132 + d0] = make_float4(acc[jr][0], acc[jr][1], acc[jr][2], acc[jr][3]);
    __syncthreads();

    // ---- softmax over k (per channel) and y = sum_k rho*(alpha+delta) ----
    {
        const int pp = t >> 7;          // point within block
        const int d = t & 127;
        float e[Kq];
        float m = -INFINITY;
#pragma unroll
        for (int kk = 0; kk < Kq; ++kk) m = fmaxf(m, sP[(pp * 16 + kk) * 132 + d]);
        m *= 0.25f;                     // exact (pow2 scale)
        float sum = 0.f;
#pragma unroll
        for (int kk = 0; kk < Kq; ++kk) {
            float ev = expf(0.25f * sP[(pp * 16 + kk) * 132 + d] - m);
            e[kk] = ev;
            sum += ev;
        }
        float rs = 1.0f / sum;
        float y = 0.f;
#pragma unroll
        for (int kk = 0; kk < Kq; ++kk) {
            int r = pp * 16 + kk;
            float a = alpha[sIdx[r] * 128 + d];
            y = fmaf(e[kk], a + sD[r * 132 + d], y);
        }
        sY[pp][d] = y * rs;
    }
    __syncthreads();

    // ---- out = y @ Wfc2 + b + in_f ----
    if (t < 128) {
        const int pp = t >> 6;
        const int q = t & 63;
        const int p = p0 + pp;
        float a = bfc2[q] + in_f[p * 64 + q];
#pragma unroll 8
        for (int d = 0; d < 128; ++d)
            a = fmaf(sY[pp][d], Wfc2[d * 64 + q], a);
        out[p * 64 + q] = a;
    }
}

// ---------------------------------------------------------------------------
extern "C" void kernel_launch(void* const* d_in, const int* in_sizes, int n_in,
                              void* d_out, int out_size, void* d_ws, size_t ws_size,
                              hipStream_t stream) {
    const float* x     = (const float*)d_in[0];
    const float* in_f  = (const float*)d_in[1];
    const float* Wfc1  = (const float*)d_in[2];
    const float* bfc1  = (const float*)d_in[3];
    const float* Wphi  = (const float*)d_in[4];
    const float* Wpsi  = (const float*)d_in[5];
    const float* Walpha= (const float*)d_in[6];
    const float* Wdpt1 = (const float*)d_in[7];
    const float* bdpt1 = (const float*)d_in[8];
    const float* Wdpt2 = (const float*)d_in[9];
    const float* bdpt2 = (const float*)d_in[10];
    const float* Wgam1 = (const float*)d_in[11];
    const float* bgam1 = (const float*)d_in[12];
    const float* Wgam2 = (const float*)d_in[13];
    const float* bgam2 = (const float*)d_in[14];
    const float* Wdel1 = (const float*)d_in[15];
    const float* bdel1 = (const float*)d_in[16];
    const float* Wdel2 = (const float*)d_in[17];
    const float* bdel2 = (const float*)d_in[18];
    const float* Wfc2  = (const float*)d_in[19];
    const float* bfc2  = (const float*)d_in[20];
    float* out = (float*)d_out;

    // workspace layout (fp32): base | psi | alpha | knn(int)  = ~25 MB
    float* base  = (float*)d_ws;
    float* psi   = base + (size_t)BNq * Dq;
    float* alpha = psi + (size_t)BNq * Dq;
    int*   knn   = (int*)(alpha + (size_t)BNq * Dq);

    knn_kernel<<<512, 256, 0, stream>>>(x, knn);
    feat_kernel<<<BNq / 16, 256, 0, stream>>>(in_f, Wfc1, bfc1, Wphi, Wpsi, Walpha,
                                              Wdpt1, bdpt1, Wdpt2, bdpt2,
                                              base, psi, alpha);
    main_kernel<<<BNq / 2, 256, 0, stream>>>(x, in_f, Wdel1, bdel1, Wdel2, bdel2,
                                             Wgam1, bgam1, Wgam2, bgam2, Wfc2, bfc2,
                                             base, psi, alpha, knn, out);
}

// Round 3
// 336.721 us; speedup vs baseline: 4.5431x; 2.2773x over previous
//
#include <hip/hip_runtime.h>
#include <hip/hip_bf16.h>
#include <math.h>

// Problem constants (fixed by setup_inputs)
#define Bq 8
#define Nq 2048
#define Pq 64
#define Dq 128
#define Kq 16
#define BNq (Bq * Nq)   // 16384 points total

typedef unsigned short u16;
typedef __bf16 bf16x8v __attribute__((ext_vector_type(8)));
typedef float f32x4v __attribute__((ext_vector_type(4)));

__device__ __forceinline__ u16 f2b(float f) {
    return __builtin_bit_cast(u16, (__bf16)f);      // RNE
}
__device__ __forceinline__ float b2f(u16 u) {
    return (float)__builtin_bit_cast(__bf16, u);
}

// ---------------------------------------------------------------------------
// Kernel 0: transpose+convert Wdel2/Wgam1/Wgam2 -> bf16 Wt, K-half-major:
// Wt[w][h][n][kk] = W_w[h*64+kk][n]   (w<3, h<2, n<128, kk<64)
// ---------------------------------------------------------------------------
__global__ __launch_bounds__(256) void prep_kernel(const float* __restrict__ Wdel2,
                                                   const float* __restrict__ Wgam1,
                                                   const float* __restrict__ Wgam2,
                                                   u16* __restrict__ Wt) {
    int idx = blockIdx.x * 256 + threadIdx.x;       // 0..49151
    int w = idx >> 14;
    int rem = idx & 16383;
    int h = rem >> 13;
    int n = (rem >> 6) & 127;
    int kk = rem & 63;
    const float* W = (w == 0) ? Wdel2 : (w == 1) ? Wgam1 : Wgam2;
    Wt[idx] = f2b(W[(h * 64 + kk) * 128 + n]);
}

// ---------------------------------------------------------------------------
// Kernel 1: exact kNN (unchanged from round 1)
// ---------------------------------------------------------------------------
__global__ __launch_bounds__(256) void knn_kernel(const float* __restrict__ x,
                                                  int* __restrict__ knn) {
    __shared__ float4 sx[Nq];                       // 32 KB
    __shared__ float sLd[32][8][17];
    __shared__ int   sLi[32][8][17];
    const int b = blockIdx.x >> 6;
    const int q0 = (blockIdx.x & 63) * 32;
    const float* xb = x + b * Nq * 3;
    for (int j = threadIdx.x; j < Nq; j += 256) {
        float x0 = xb[j * 3 + 0], x1 = xb[j * 3 + 1], x2 = xb[j * 3 + 2];
        float n2 = __fadd_rn(__fadd_rn(__fmul_rn(x0, x0), __fmul_rn(x1, x1)),
                             __fmul_rn(x2, x2));
        sx[j] = make_float4(x0, x1, x2, n2);
    }
    __syncthreads();
    const int q = threadIdx.x & 31;
    const int sub = threadIdx.x >> 5;
    const float4 qv = sx[q0 + q];
    float bd[Kq];
    int bj[Kq];
#pragma unroll
    for (int s = 0; s < Kq; ++s) { bd[s] = INFINITY; bj[s] = 0; }
    const int j0 = sub * 256;
    for (int i = 0; i < 256; ++i) {
        const int j = j0 + i;
        float4 p = sx[j];
        float dot = __fadd_rn(__fadd_rn(__fmul_rn(qv.x, p.x), __fmul_rn(qv.y, p.y)),
                              __fmul_rn(qv.z, p.z));
        float d = __fsub_rn(__fadd_rn(qv.w, p.w), __fmul_rn(2.0f, dot));
        if (d < bd[Kq - 1]) {
            bd[Kq - 1] = d; bj[Kq - 1] = j;
#pragma unroll
            for (int s = Kq - 1; s >= 1; --s) {
                if (bd[s] < bd[s - 1]) {
                    float td = bd[s]; bd[s] = bd[s - 1]; bd[s - 1] = td;
                    int tj = bj[s]; bj[s] = bj[s - 1]; bj[s - 1] = tj;
                }
            }
        }
    }
#pragma unroll
    for (int s = 0; s < Kq; ++s) { sLd[q][sub][s] = bd[s]; sLi[q][sub][s] = bj[s]; }
    __syncthreads();
    if (threadIdx.x < 32) {
        const int mq = threadIdx.x;
        int pos[8]; float hd[8]; int hi[8];
#pragma unroll
        for (int s = 0; s < 8; ++s) {
            pos[s] = 1; hd[s] = sLd[mq][s][0]; hi[s] = sLi[mq][s][0];
        }
        int* o = knn + (b * Nq + q0 + mq) * Kq;
#pragma unroll
        for (int oi = 0; oi < Kq; ++oi) {
            float bdv = hd[0]; int biv = hi[0]; int bs = 0;
#pragma unroll
            for (int s = 1; s < 8; ++s) {
                bool take = (hd[s] < bdv) || (hd[s] == bdv && hi[s] < biv);
                if (take) { bdv = hd[s]; biv = hi[s]; bs = s; }
            }
            o[oi] = biv;
#pragma unroll
            for (int s = 0; s < 8; ++s) {
                if (s == bs) {
                    int pp = pos[s] < Kq ? pos[s] : (Kq - 1);
                    bool ok = pos[s] < Kq;
                    hd[s] = ok ? sLd[mq][s][pp] : INFINITY;
                    hi[s] = ok ? sLi[mq][s][pp] : 0x7fffffff;
                    pos[s]++;
                }
            }
        }
    }
}

// ---------------------------------------------------------------------------
// fp32 LDS-broadcast matmul tile (feat kernel only)
// ---------------------------------------------------------------------------
template <int INNER, int RPT, int WROWS, int SSTR>
__device__ __forceinline__ void mm_tile(const float* __restrict__ Wg,
                                        const float* __restrict__ sSrc,
                                        float* __restrict__ Wbuf,
                                        int rg, int d0, float (&acc)[RPT][4]) {
    constexpr int NST = INNER / WROWS;
    for (int st = 0; st < NST; ++st) {
        __syncthreads();
        for (int idx = threadIdx.x; idx < WROWS * 128; idx += 256)
            Wbuf[idx] = Wg[st * WROWS * 128 + idx];
        __syncthreads();
#pragma unroll
        for (int i4 = 0; i4 < WROWS; i4 += 4) {
            const int i = st * WROWS + i4;
            float4 w0 = *(const float4*)&Wbuf[(i4 + 0) * 128 + d0];
            float4 w1 = *(const float4*)&Wbuf[(i4 + 1) * 128 + d0];
            float4 w2 = *(const float4*)&Wbuf[(i4 + 2) * 128 + d0];
            float4 w3 = *(const float4*)&Wbuf[(i4 + 3) * 128 + d0];
#pragma unroll
            for (int jr = 0; jr < RPT; ++jr) {
                const float4 h = *(const float4*)&sSrc[(rg * RPT + jr) * SSTR + i];
                acc[jr][0] = fmaf(h.x, w0.x, fmaf(h.y, w1.x, fmaf(h.z, w2.x, fmaf(h.w, w3.x, acc[jr][0]))));
                acc[jr][1] = fmaf(h.x, w0.y, fmaf(h.y, w1.y, fmaf(h.z, w2.y, fmaf(h.w, w3.y, acc[jr][1]))));
                acc[jr][2] = fmaf(h.x, w0.z, fmaf(h.y, w1.z, fmaf(h.z, w2.z, fmaf(h.w, w3.z, acc[jr][2]))));
                acc[jr][3] = fmaf(h.x, w0.w, fmaf(h.y, w1.w, fmaf(h.z, w2.w, fmaf(h.w, w3.w, acc[jr][3]))));
            }
        }
    }
}

// ---------------------------------------------------------------------------
// Kernel 2: per-point features (psi/alpha now stored bf16; base fp32)
// ---------------------------------------------------------------------------
__global__ __launch_bounds__(256) void feat_kernel(
    const float* __restrict__ in_f,
    const float* __restrict__ Wfc1, const float* __restrict__ bfc1,
    const float* __restrict__ Wphi, const float* __restrict__ Wpsi,
    const float* __restrict__ Walpha,
    const float* __restrict__ Wdpt1, const float* __restrict__ bdpt1,
    const float* __restrict__ Wdpt2, const float* __restrict__ bdpt2,
    float* __restrict__ base, u16* __restrict__ psiB, u16* __restrict__ alphaB) {
    __shared__ __align__(16) float sIn[16 * 68];
    __shared__ __align__(16) float sF[16 * 132];
    __shared__ __align__(16) float sT[16 * 132];
    __shared__ __align__(16) float sP[16 * 132];
    __shared__ __align__(16) float Wbuf[32 * 128];
    const int t = threadIdx.x;
    const int p0 = blockIdx.x * 16;
    const int rg = t >> 5;
    const int d0 = (t & 31) * 4;

    for (int idx = t; idx < 16 * 64; idx += 256) {
        int r = idx >> 6, i = idx & 63;
        sIn[r * 68 + i] = in_f[(p0 + r) * 64 + i];
    }

    float acc[2][4];
    float4 bb;

    // f = in_f @ Wfc1 + b
    bb = *(const float4*)&bfc1[d0];
#pragma unroll
    for (int jr = 0; jr < 2; ++jr) { acc[jr][0] = bb.x; acc[jr][1] = bb.y; acc[jr][2] = bb.z; acc[jr][3] = bb.w; }
    mm_tile<64, 2, 32, 68>(Wfc1, sIn, Wbuf, rg, d0, acc);
    __syncthreads();
#pragma unroll
    for (int jr = 0; jr < 2; ++jr)
        *(float4*)&sF[(rg * 2 + jr) * 132 + d0] = make_float4(acc[jr][0], acc[jr][1], acc[jr][2], acc[jr][3]);

    // phi = f @ Wphi (LDS)
#pragma unroll
    for (int jr = 0; jr < 2; ++jr) { acc[jr][0] = 0; acc[jr][1] = 0; acc[jr][2] = 0; acc[jr][3] = 0; }
    mm_tile<128, 2, 32, 132>(Wphi, sF, Wbuf, rg, d0, acc);
    __syncthreads();
#pragma unroll
    for (int jr = 0; jr < 2; ++jr)
        *(float4*)&sP[(rg * 2 + jr) * 132 + d0] = make_float4(acc[jr][0], acc[jr][1], acc[jr][2], acc[jr][3]);

    // psi = f @ Wpsi -> bf16
#pragma unroll
    for (int jr = 0; jr < 2; ++jr) { acc[jr][0] = 0; acc[jr][1] = 0; acc[jr][2] = 0; acc[jr][3] = 0; }
    mm_tile<128, 2, 32, 132>(Wpsi, sF, Wbuf, rg, d0, acc);
#pragma unroll
    for (int jr = 0; jr < 2; ++jr) {
        ushort4 pk = make_ushort4(f2b(acc[jr][0]), f2b(acc[jr][1]), f2b(acc[jr][2]), f2b(acc[jr][3]));
        *(ushort4*)&psiB[(p0 + rg * 2 + jr) * 128 + d0] = pk;
    }

    // alpha = f @ Walpha -> bf16
#pragma unroll
    for (int jr = 0; jr < 2; ++jr) { acc[jr][0] = 0; acc[jr][1] = 0; acc[jr][2] = 0; acc[jr][3] = 0; }
    mm_tile<128, 2, 32, 132>(Walpha, sF, Wbuf, rg, d0, acc);
#pragma unroll
    for (int jr = 0; jr < 2; ++jr) {
        ushort4 pk = make_ushort4(f2b(acc[jr][0]), f2b(acc[jr][1]), f2b(acc[jr][2]), f2b(acc[jr][3]));
        *(ushort4*)&alphaB[(p0 + rg * 2 + jr) * 128 + d0] = pk;
    }

    // t1 = relu(f @ Wdpt1 + b)
    bb = *(const float4*)&bdpt1[d0];
#pragma unroll
    for (int jr = 0; jr < 2; ++jr) { acc[jr][0] = bb.x; acc[jr][1] = bb.y; acc[jr][2] = bb.z; acc[jr][3] = bb.w; }
    mm_tile<128, 2, 32, 132>(Wdpt1, sF, Wbuf, rg, d0, acc);
    __syncthreads();
#pragma unroll
    for (int jr = 0; jr < 2; ++jr)
        *(float4*)&sT[(rg * 2 + jr) * 132 + d0] =
            make_float4(fmaxf(acc[jr][0], 0.f), fmaxf(acc[jr][1], 0.f), fmaxf(acc[jr][2], 0.f), fmaxf(acc[jr][3], 0.f));

    // base = phi + t1 @ Wdpt2 + b -> fp32
    bb = *(const float4*)&bdpt2[d0];
#pragma unroll
    for (int jr = 0; jr < 2; ++jr) { acc[jr][0] = bb.x; acc[jr][1] = bb.y; acc[jr][2] = bb.z; acc[jr][3] = bb.w; }
    mm_tile<128, 2, 32, 132>(Wdpt2, sT, Wbuf, rg, d0, acc);
#pragma unroll
    for (int jr = 0; jr < 2; ++jr) {
        int r = rg * 2 + jr;
        float4 ph = *(const float4*)&sP[r * 132 + d0];
        *(float4*)&base[(p0 + r) * 128 + d0] =
            make_float4(acc[jr][0] + ph.x, acc[jr][1] + ph.y, acc[jr][2] + ph.z, acc[jr][3] + ph.w);
    }
}

// ---------------------------------------------------------------------------
// Kernel 3 (MFMA): 4 points/block = 64 rows. Grid 4096 x 256 threads (4 waves).
// Stages del2 -> gam1 -> gam2 as [64x128]@[128x128] bf16 MFMA; delta & gamma
// stay in wave accumulators; softmax over k is wave-local (shfl_xor 16/32).
// LDS: sA/sBP [64][128] bf16 XOR-swizzled (byte ^= (row&7)<<4), sW [128][64].
// ---------------------------------------------------------------------------
__device__ __forceinline__ void stage_w(const u16* __restrict__ Wh, u16* sW, int t) {
#pragma unroll
    for (int c = 0; c < 4; ++c) {
        int lin = c * 4096 + t * 16;                 // byte in 16 KB half
        int n = lin >> 7;
        int o = lin & 127;
        bf16x8v v = *(const bf16x8v*)(Wh + (lin >> 1));
        *(bf16x8v*)((char*)sW + n * 128 + (o ^ ((n & 7) << 4))) = v;
    }
}

__device__ __forceinline__ void do_stage(const u16* __restrict__ Wt_stage,
                                         const u16* sA, u16* sW,
                                         int t, int w, int lane,
                                         f32x4v (&acc)[4][2]) {
    const int kg = lane >> 4;
    const int l15 = lane & 15;
#pragma unroll
    for (int h = 0; h < 2; ++h) {
        __syncthreads();                             // prev sW reads done
        stage_w(Wt_stage + h * 8192, sW, t);
        __syncthreads();                             // sW (and pending sA) ready
#pragma unroll
        for (int ks = 0; ks < 2; ++ks) {
            bf16x8v a[4], bfr[2];
#pragma unroll
            for (int m = 0; m < 4; ++m) {
                int row = m * 16 + l15;
                int o = h * 128 + ks * 64 + kg * 16;
                a[m] = *(const bf16x8v*)((const char*)sA + row * 256 + (o ^ ((row & 7) << 4)));
            }
#pragma unroll
            for (int nt = 0; nt < 2; ++nt) {
                int n = w * 32 + nt * 16 + l15;
                int o = ks * 64 + kg * 16;
                bfr[nt] = *(const bf16x8v*)((const char*)sW + n * 128 + (o ^ ((n & 7) << 4)));
            }
#pragma unroll
            for (int m = 0; m < 4; ++m)
#pragma unroll
                for (int nt = 0; nt < 2; ++nt)
                    acc[m][nt] = __builtin_amdgcn_mfma_f32_16x16x32_bf16(a[m], bfr[nt], acc[m][nt], 0, 0, 0);
        }
    }
}

__global__ __launch_bounds__(256, 2) void main_kernel(
    const float* __restrict__ x, const float* __restrict__ in_f,
    const float* __restrict__ Wdel1, const float* __restrict__ bdel1,
    const float* __restrict__ bdel2,
    const float* __restrict__ bgam1, const float* __restrict__ bgam2,
    const float* __restrict__ Wfc2, const float* __restrict__ bfc2,
    const float* __restrict__ base, const u16* __restrict__ psiB,
    const u16* __restrict__ alphaB, const int* __restrict__ knn,
    const u16* __restrict__ Wt, float* __restrict__ out) {
    __shared__ __align__(16) u16 sA[64 * 128];       // h1 -> pre -> g1 (swizzled)
    __shared__ __align__(16) u16 sBP[64 * 128];      // base-psi -> alpha (swizzled)
    __shared__ __align__(16) u16 sW[128 * 64];       // weight K-half (swizzled)
    __shared__ float sWd1[512];                      // Wdel1 rows 0..2, bias at 384
    __shared__ float sDiff[64][3];
    __shared__ int sIdx[64];
    __shared__ float sY[4][128];

    const int t = threadIdx.x;
    const int lane = t & 63;
    const int w = t >> 6;                            // wave id: cols w*32..w*32+31
    const int kg = lane >> 4;
    const int l15 = lane & 15;
    const int p0 = blockIdx.x * 4;                   // 4 points per block
    const int b = p0 >> 11;

    // ---- phase A: indices, diffs, Wdel1 stage ----
    if (t < 64) {
        int p = p0 + (t >> 4);
        int j = knn[p * Kq + (t & 15)];
        sIdx[t] = b * Nq + j;
        const float* xq = x + p * 3;
        const float* xn = x + ((size_t)(b * Nq + j)) * 3;
        sDiff[t][0] = xq[0] - xn[0];
        sDiff[t][1] = xq[1] - xn[1];
        sDiff[t][2] = xq[2] - xn[2];
    }
#pragma unroll
    for (int i = 0; i < 2; ++i) {
        int idx = t + i * 256;
        sWd1[idx] = (idx < 384) ? Wdel1[idx] : bdel1[idx - 384];
    }
    __syncthreads();

    // ---- phase B: h1 -> sA, base-psi -> sBP, alpha -> regs ----
    const int r = t >> 2;                            // row 0..63
    const int cb = t & 3;                            // col block (32 cols)
    const float dx = sDiff[r][0], dy = sDiff[r][1], dz = sDiff[r][2];
    const int nrow = sIdx[r];
    const int prow = p0 + (r >> 4);
    bf16x8v aStash[4];
#pragma unroll
    for (int c8 = 0; c8 < 4; ++c8) {
        const int col0 = cb * 32 + c8 * 8;
        const int obyte = (col0 * 2) ^ ((r & 7) << 4);
        // h1
        bf16x8v hv;
#pragma unroll
        for (int j = 0; j < 8; ++j) {
            int cc = col0 + j;
            float v = fmaf(dz, sWd1[256 + cc], fmaf(dy, sWd1[128 + cc], fmaf(dx, sWd1[cc], sWd1[384 + cc])));
            hv[j] = (__bf16)fmaxf(v, 0.f);
        }
        *(bf16x8v*)((char*)sA + r * 256 + obyte) = hv;
        // bp = base - psi
        bf16x8v ps = *(const bf16x8v*)&psiB[(size_t)nrow * 128 + col0];
        float4 b0 = *(const float4*)&base[(size_t)prow * 128 + col0];
        float4 b1 = *(const float4*)&base[(size_t)prow * 128 + col0 + 4];
        bf16x8v bp;
        bp[0] = (__bf16)(b0.x - (float)ps[0]); bp[1] = (__bf16)(b0.y - (float)ps[1]);
        bp[2] = (__bf16)(b0.z - (float)ps[2]); bp[3] = (__bf16)(b0.w - (float)ps[3]);
        bp[4] = (__bf16)(b1.x - (float)ps[4]); bp[5] = (__bf16)(b1.y - (float)ps[5]);
        bp[6] = (__bf16)(b1.z - (float)ps[6]); bp[7] = (__bf16)(b1.w - (float)ps[7]);
        *(bf16x8v*)((char*)sBP + r * 256 + obyte) = bp;
        // alpha (hold in regs until sBP is free)
        aStash[c8] = *(const bf16x8v*)&alphaB[(size_t)nrow * 128 + col0];
    }

    // ---- del2: delta = h1 @ Wdel2 + b (stays in accD) ----
    f32x4v accD[4][2], accW[4][2];
    {
        float bv0 = bdel2[w * 32 + l15];
        float bv1 = bdel2[w * 32 + 16 + l15];
#pragma unroll
        for (int m = 0; m < 4; ++m) { accD[m][0] = f32x4v{bv0, bv0, bv0, bv0}; accD[m][1] = f32x4v{bv1, bv1, bv1, bv1}; }
    }
    do_stage(Wt + 0, sA, sW, t, w, lane, accD);
    __syncthreads();                                 // all sA(h1) reads done

    // ---- pre = delta + bp -> sA (wave-local region) ----
#pragma unroll
    for (int m = 0; m < 4; ++m)
#pragma unroll
        for (int nt = 0; nt < 2; ++nt)
#pragma unroll
            for (int rr = 0; rr < 4; ++rr) {
                int row = m * 16 + kg * 4 + rr;
                int col = w * 32 + nt * 16 + l15;
                int off = row * 256 + ((col * 2) ^ ((row & 7) << 4));
                float bp = (float)*(const __bf16*)((const char*)sBP + off);
                *(__bf16*)((char*)sA + off) = (__bf16)(accD[m][nt][rr] + bp);
            }
    __syncthreads();                                 // all bp reads done

    // ---- stash alpha into sBP (sBP free now) ----
#pragma unroll
    for (int c8 = 0; c8 < 4; ++c8) {
        const int col0 = cb * 32 + c8 * 8;
        *(bf16x8v*)((char*)sBP + r * 256 + ((col0 * 2) ^ ((r & 7) << 4))) = aStash[c8];
    }

    // ---- gam1: g1 = relu(pre @ Wgam1 + b) ----
    {
        float bv0 = bgam1[w * 32 + l15];
        float bv1 = bgam1[w * 32 + 16 + l15];
#pragma unroll
        for (int m = 0; m < 4; ++m) { accW[m][0] = f32x4v{bv0, bv0, bv0, bv0}; accW[m][1] = f32x4v{bv1, bv1, bv1, bv1}; }
    }
    do_stage(Wt + 16384, sA, sW, t, w, lane, accW);
    __syncthreads();                                 // all sA(pre) reads done

    // ---- g1 -> sA ----
#pragma unroll
    for (int m = 0; m < 4; ++m)
#pragma unroll
        for (int nt = 0; nt < 2; ++nt)
#pragma unroll
            for (int rr = 0; rr < 4; ++rr) {
                int row = m * 16 + kg * 4 + rr;
                int col = w * 32 + nt * 16 + l15;
                int off = row * 256 + ((col * 2) ^ ((row & 7) << 4));
                *(__bf16*)((char*)sA + off) = (__bf16)fmaxf(accW[m][nt][rr], 0.f);
            }

    // ---- gam2: gamma = g1 @ Wgam2 + b ----
    {
        float bv0 = bgam2[w * 32 + l15];
        float bv1 = bgam2[w * 32 + 16 + l15];
#pragma unroll
        for (int m = 0; m < 4; ++m) { accW[m][0] = f32x4v{bv0, bv0, bv0, bv0}; accW[m][1] = f32x4v{bv1, bv1, bv1, bv1}; }
    }
    do_stage(Wt + 32768, sA, sW, t, w, lane, accW);  // internal barriers cover sA writes

    // ---- softmax over k (16 rows per point = one m-tile) + y ----
#pragma unroll
    for (int m = 0; m < 4; ++m)
#pragma unroll
        for (int nt = 0; nt < 2; ++nt) {
            const int col = w * 32 + nt * 16 + l15;
            float g0 = accW[m][nt][0], g1v = accW[m][nt][1], g2 = accW[m][nt][2], g3 = accW[m][nt][3];
            float mx = fmaxf(fmaxf(g0, g1v), fmaxf(g2, g3));
            mx = fmaxf(mx, __shfl_xor(mx, 16, 64));
            mx = fmaxf(mx, __shfl_xor(mx, 32, 64));
            float m4 = mx * 0.25f;
            float e0 = expf(0.25f * g0 - m4), e1 = expf(0.25f * g1v - m4);
            float e2 = expf(0.25f * g2 - m4), e3 = expf(0.25f * g3 - m4);
            float s = e0 + e1 + e2 + e3;
            s += __shfl_xor(s, 16, 64);
            s += __shfl_xor(s, 32, 64);
            float y = 0.f;
#pragma unroll
            for (int rr = 0; rr < 4; ++rr) {
                int row = m * 16 + kg * 4 + rr;
                int off = row * 256 + ((col * 2) ^ ((row & 7) << 4));
                float al = (float)*(const __bf16*)((const char*)sBP + off);
                float ev = (rr == 0) ? e0 : (rr == 1) ? e1 : (rr == 2) ? e2 : e3;
                y = fmaf(ev, al + accD[m][nt][rr], y);
            }
            y += __shfl_xor(y, 16, 64);
            y += __shfl_xor(y, 32, 64);
            if (kg == 0) sY[m][col] = y / s;
        }
    __syncthreads();

    // ---- out = y @ Wfc2 + b + in_f ----
    {
        const int p = t >> 6;                        // 0..3
        const int q = t & 63;
        const int gp = p0 + p;
        float a = bfc2[q] + in_f[(size_t)gp * 64 + q];
#pragma unroll 8
        for (int d = 0; d < 128; ++d)
            a = fmaf(sY[p][d], Wfc2[d * 64 + q], a);
        out[(size_t)gp * 64 + q] = a;
    }
}

// ---------------------------------------------------------------------------
extern "C" void kernel_launch(void* const* d_in, const int* in_sizes, int n_in,
                              void* d_out, int out_size, void* d_ws, size_t ws_size,
                              hipStream_t stream) {
    const float* x     = (const float*)d_in[0];
    const float* in_f  = (const float*)d_in[1];
    const float* Wfc1  = (const float*)d_in[2];
    const float* bfc1  = (const float*)d_in[3];
    const float* Wphi  = (const float*)d_in[4];
    const float* Wpsi  = (const float*)d_in[5];
    const float* Walpha= (const float*)d_in[6];
    const float* Wdpt1 = (const float*)d_in[7];
    const float* bdpt1 = (const float*)d_in[8];
    const float* Wdpt2 = (const float*)d_in[9];
    const float* bdpt2 = (const float*)d_in[10];
    const float* Wgam1 = (const float*)d_in[11];
    const float* bgam1 = (const float*)d_in[12];
    const float* Wgam2 = (const float*)d_in[13];
    const float* bgam2 = (const float*)d_in[14];
    const float* Wdel1 = (const float*)d_in[15];
    const float* bdel1 = (const float*)d_in[16];
    const float* Wdel2 = (const float*)d_in[17];
    const float* bdel2 = (const float*)d_in[18];
    const float* Wfc2  = (const float*)d_in[19];
    const float* bfc2  = (const float*)d_in[20];
    float* out = (float*)d_out;

    // ws: base f32 (8MB) | psiB bf16 (4MB) | alphaB bf16 (4MB) | knn int (1MB) | Wt bf16 (96KB)
    float* base   = (float*)d_ws;
    u16*   psiB   = (u16*)(base + (size_t)BNq * Dq);
    u16*   alphaB = psiB + (size_t)BNq * Dq;
    int*   knn    = (int*)(alphaB + (size_t)BNq * Dq);
    u16*   Wt     = (u16*)(knn + (size_t)BNq * Kq);

    prep_kernel<<<192, 256, 0, stream>>>(Wdel2, Wgam1, Wgam2, Wt);
    knn_kernel<<<512, 256, 0, stream>>>(x, knn);
    feat_kernel<<<BNq / 16, 256, 0, stream>>>(in_f, Wfc1, bfc1, Wphi, Wpsi, Walpha,
                                              Wdpt1, bdpt1, Wdpt2, bdpt2,
                                              base, psiB, alphaB);
    main_kernel<<<BNq / 4, 256, 0, stream>>>(x, in_f, Wdel1, bdel1, bdel2,
                                             bgam1, bgam2, Wfc2, bfc2,
                                             base, psiB, alphaB, knn, Wt, out);
}

// Round 4
// 238.898 us; speedup vs baseline: 6.4034x; 1.4095x over previous
//
#include <hip/hip_runtime.h>
#include <hip/hip_bf16.h>
#include <math.h>

// Problem constants (fixed by setup_inputs)
#define Bq 8
#define Nq 2048
#define Pq 64
#define Dq 128
#define Kq 16
#define BNq (Bq * Nq)   // 16384 points total

typedef unsigned short u16;
typedef __bf16 bf16x8v __attribute__((ext_vector_type(8)));
typedef float f32x4v __attribute__((ext_vector_type(4)));

__device__ __forceinline__ u16 f2b(float f) {
    return __builtin_bit_cast(u16, (__bf16)f);      // RNE
}

// Wt element offsets (all matrices stored transposed bf16: Wt[n][k] = W[k][n])
#define OFF_DEL2 0
#define OFF_GAM1 16384
#define OFF_GAM2 32768
#define OFF_FC1  49152
#define OFF_PHI  57344
#define OFF_PSI  73728
#define OFF_ALF  90112
#define OFF_DPT1 106496
#define OFF_DPT2 122880
#define WT_TOTAL 139264

// ---------------------------------------------------------------------------
// Kernel 0: transpose+convert all 9 matmul weights -> bf16 Wt[n][K] linear.
// All source weights are [K][128] row-major (Wfc1 is [64][128]).
// ---------------------------------------------------------------------------
__global__ __launch_bounds__(256) void prep_kernel(
    const float* __restrict__ Wdel2, const float* __restrict__ Wgam1,
    const float* __restrict__ Wgam2, const float* __restrict__ Wfc1,
    const float* __restrict__ Wphi, const float* __restrict__ Wpsi,
    const float* __restrict__ Walpha, const float* __restrict__ Wdpt1,
    const float* __restrict__ Wdpt2, u16* __restrict__ Wt) {
    int idx = blockIdx.x * 256 + threadIdx.x;       // 0..139263
    const float* W;
    int n, k;
    if (idx < OFF_FC1) {
        int m = idx >> 14, r = idx & 16383;
        W = (m == 0) ? Wdel2 : (m == 1) ? Wgam1 : Wgam2;
        n = r >> 7; k = r & 127;
    } else if (idx < OFF_PHI) {
        int r = idx - OFF_FC1;
        W = Wfc1; n = r >> 6; k = r & 63;
    } else {
        int r = idx - OFF_PHI;
        int m = r >> 14; r &= 16383;
        W = (m == 0) ? Wphi : (m == 1) ? Wpsi : (m == 2) ? Walpha : (m == 3) ? Wdpt1 : Wdpt2;
        n = r >> 7; k = r & 127;
    }
    Wt[idx] = f2b(W[k * 128 + n]);
}

// ---------------------------------------------------------------------------
// Kernel 1: exact kNN (unchanged from round 1)
// ---------------------------------------------------------------------------
__global__ __launch_bounds__(256) void knn_kernel(const float* __restrict__ x,
                                                  int* __restrict__ knn) {
    __shared__ float4 sx[Nq];                       // 32 KB
    __shared__ float sLd[32][8][17];
    __shared__ int   sLi[32][8][17];
    const int b = blockIdx.x >> 6;
    const int q0 = (blockIdx.x & 63) * 32;
    const float* xb = x + b * Nq * 3;
    for (int j = threadIdx.x; j < Nq; j += 256) {
        float x0 = xb[j * 3 + 0], x1 = xb[j * 3 + 1], x2 = xb[j * 3 + 2];
        float n2 = __fadd_rn(__fadd_rn(__fmul_rn(x0, x0), __fmul_rn(x1, x1)),
                             __fmul_rn(x2, x2));
        sx[j] = make_float4(x0, x1, x2, n2);
    }
    __syncthreads();
    const int q = threadIdx.x & 31;
    const int sub = threadIdx.x >> 5;
    const float4 qv = sx[q0 + q];
    float bd[Kq];
    int bj[Kq];
#pragma unroll
    for (int s = 0; s < Kq; ++s) { bd[s] = INFINITY; bj[s] = 0; }
    const int j0 = sub * 256;
    for (int i = 0; i < 256; ++i) {
        const int j = j0 + i;
        float4 p = sx[j];
        float dot = __fadd_rn(__fadd_rn(__fmul_rn(qv.x, p.x), __fmul_rn(qv.y, p.y)),
                              __fmul_rn(qv.z, p.z));
        float d = __fsub_rn(__fadd_rn(qv.w, p.w), __fmul_rn(2.0f, dot));
        if (d < bd[Kq - 1]) {
            bd[Kq - 1] = d; bj[Kq - 1] = j;
#pragma unroll
            for (int s = Kq - 1; s >= 1; --s) {
                if (bd[s] < bd[s - 1]) {
                    float td = bd[s]; bd[s] = bd[s - 1]; bd[s - 1] = td;
                    int tj = bj[s]; bj[s] = bj[s - 1]; bj[s - 1] = tj;
                }
            }
        }
    }
#pragma unroll
    for (int s = 0; s < Kq; ++s) { sLd[q][sub][s] = bd[s]; sLi[q][sub][s] = bj[s]; }
    __syncthreads();
    if (threadIdx.x < 32) {
        const int mq = threadIdx.x;
        int pos[8]; float hd[8]; int hi[8];
#pragma unroll
        for (int s = 0; s < 8; ++s) {
            pos[s] = 1; hd[s] = sLd[mq][s][0]; hi[s] = sLi[mq][s][0];
        }
        int* o = knn + (b * Nq + q0 + mq) * Kq;
#pragma unroll
        for (int oi = 0; oi < Kq; ++oi) {
            float bdv = hd[0]; int biv = hi[0]; int bs = 0;
#pragma unroll
            for (int s = 1; s < 8; ++s) {
                bool take = (hd[s] < bdv) || (hd[s] == bdv && hi[s] < biv);
                if (take) { bdv = hd[s]; biv = hi[s]; bs = s; }
            }
            o[oi] = biv;
#pragma unroll
            for (int s = 0; s < 8; ++s) {
                if (s == bs) {
                    int pp = pos[s] < Kq ? pos[s] : (Kq - 1);
                    bool ok = pos[s] < Kq;
                    hd[s] = ok ? sLd[mq][s][pp] : INFINITY;
                    hi[s] = ok ? sLi[mq][s][pp] : 0x7fffffff;
                    pos[s]++;
                }
            }
        }
    }
}

// ---------------------------------------------------------------------------
// Shared MFMA helpers. LDS tiles are row-major with XOR swizzle
// byte ^= (row&7)<<4 (16B granules), rows 256B (K=128) or 128B (K=64).
// ---------------------------------------------------------------------------
template <int BYTES, int ROWBYTES>
__device__ __forceinline__ void stageW(const u16* __restrict__ src,
                                       u16* __restrict__ sW, int t) {
#pragma unroll
    for (int c = 0; c < BYTES / 4096; ++c) {
        int lin = c * 4096 + t * 16;
        int n = lin / ROWBYTES;
        int o = lin % ROWBYTES;
        bf16x8v v = *(const bf16x8v*)((const char*)src + lin);
        *(bf16x8v*)((char*)sW + n * ROWBYTES + (o ^ ((n & 7) << 4))) = v;
    }
}

__device__ __forceinline__ void mfma_k128(const u16* __restrict__ sA,
                                          const u16* __restrict__ sW,
                                          int colbase, int lane,
                                          f32x4v (&acc)[4][2]) {
    const int kg = lane >> 4;
    const int l15 = lane & 15;
#pragma unroll
    for (int ks = 0; ks < 4; ++ks) {
        bf16x8v a[4], bfr[2];
#pragma unroll
        for (int m = 0; m < 4; ++m) {
            int row = m * 16 + l15;
            int o = (ks * 64 + kg * 16) ^ ((row & 7) << 4);
            a[m] = *(const bf16x8v*)((const char*)sA + row * 256 + o);
        }
#pragma unroll
        for (int nt = 0; nt < 2; ++nt) {
            int n = colbase + nt * 16 + l15;
            int o = (ks * 64 + kg * 16) ^ ((n & 7) << 4);
            bfr[nt] = *(const bf16x8v*)((const char*)sW + n * 256 + o);
        }
#pragma unroll
        for (int m = 0; m < 4; ++m)
#pragma unroll
            for (int nt = 0; nt < 2; ++nt)
                acc[m][nt] = __builtin_amdgcn_mfma_f32_16x16x32_bf16(a[m], bfr[nt], acc[m][nt], 0, 0, 0);
    }
}

__device__ __forceinline__ void mfma_k64(const u16* __restrict__ sA,
                                         const u16* __restrict__ sW,
                                         int colbase, int lane,
                                         f32x4v (&acc)[4][2]) {
    const int kg = lane >> 4;
    const int l15 = lane & 15;
#pragma unroll
    for (int ks = 0; ks < 2; ++ks) {
        bf16x8v a[4], bfr[2];
#pragma unroll
        for (int m = 0; m < 4; ++m) {
            int row = m * 16 + l15;
            int o = (ks * 64 + kg * 16) ^ ((row & 7) << 4);
            a[m] = *(const bf16x8v*)((const char*)sA + row * 128 + o);
        }
#pragma unroll
        for (int nt = 0; nt < 2; ++nt) {
            int n = colbase + nt * 16 + l15;
            int o = (ks * 64 + kg * 16) ^ ((n & 7) << 4);
            bfr[nt] = *(const bf16x8v*)((const char*)sW + n * 128 + o);
        }
#pragma unroll
        for (int m = 0; m < 4; ++m)
#pragma unroll
            for (int nt = 0; nt < 2; ++nt)
                acc[m][nt] = __builtin_amdgcn_mfma_f32_16x16x32_bf16(a[m], bfr[nt], acc[m][nt], 0, 0, 0);
    }
}

// ---------------------------------------------------------------------------
// Kernel 2 (MFMA): per-point features, 64 points/block, 256 blocks x 4 waves.
// fc1 -> f(sF); phi kept in regs; psi/alpha -> bf16 global; dpt1 -> t1(sF
// in place); dpt2 + phi + bias -> base fp32. LDS 56 KB.
// ---------------------------------------------------------------------------
__global__ __launch_bounds__(256, 2) void feat_kernel(
    const float* __restrict__ in_f, const u16* __restrict__ Wt,
    const float* __restrict__ bfc1, const float* __restrict__ bdpt1,
    const float* __restrict__ bdpt2,
    float* __restrict__ base, u16* __restrict__ psiB, u16* __restrict__ alphaB) {
    __shared__ __align__(16) u16 sIn[64 * 64];      // 8 KB (128B rows)
    __shared__ __align__(16) u16 sF[64 * 128];      // 16 KB (256B rows)
    __shared__ __align__(16) u16 sW[128 * 128];     // 32 KB
    const int t = threadIdx.x;
    const int lane = t & 63;
    const int w = t >> 6;
    const int kg = lane >> 4;
    const int l15 = lane & 15;
    const int p0 = blockIdx.x * 64;

    // ---- load in_f -> sIn bf16 swizzled ----
    {
        const int r = t >> 2;
        const int c0 = (t & 3) * 16;
        const float* src = &in_f[(size_t)(p0 + r) * 64 + c0];
        float4 v0 = *(const float4*)(src + 0);
        float4 v1 = *(const float4*)(src + 4);
        float4 v2 = *(const float4*)(src + 8);
        float4 v3 = *(const float4*)(src + 12);
        bf16x8v lo, hi;
        lo[0] = (__bf16)v0.x; lo[1] = (__bf16)v0.y; lo[2] = (__bf16)v0.z; lo[3] = (__bf16)v0.w;
        lo[4] = (__bf16)v1.x; lo[5] = (__bf16)v1.y; lo[6] = (__bf16)v1.z; lo[7] = (__bf16)v1.w;
        hi[0] = (__bf16)v2.x; hi[1] = (__bf16)v2.y; hi[2] = (__bf16)v2.z; hi[3] = (__bf16)v2.w;
        hi[4] = (__bf16)v3.x; hi[5] = (__bf16)v3.y; hi[6] = (__bf16)v3.z; hi[7] = (__bf16)v3.w;
        const int swz = (r & 7) << 4;
        *(bf16x8v*)((char*)sIn + r * 128 + ((c0 * 2) ^ swz)) = lo;
        *(bf16x8v*)((char*)sIn + r * 128 + (((c0 + 8) * 2) ^ swz)) = hi;
    }

    f32x4v acc[4][2], accPhi[4][2];

    // ---- fc1: f = in_f @ Wfc1 + b ----
    {
        float bv0 = bfc1[w * 32 + l15];
        float bv1 = bfc1[w * 32 + 16 + l15];
#pragma unroll
        for (int m = 0; m < 4; ++m) { acc[m][0] = f32x4v{bv0, bv0, bv0, bv0}; acc[m][1] = f32x4v{bv1, bv1, bv1, bv1}; }
    }
    stageW<16384, 128>(Wt + OFF_FC1, sW, t);
    __syncthreads();                                 // sIn + sW ready
    mfma_k64(sIn, sW, w * 32, lane, acc);

    // ---- f -> sF (bf16, swizzled) ----
#pragma unroll
    for (int m = 0; m < 4; ++m)
#pragma unroll
        for (int nt = 0; nt < 2; ++nt)
#pragma unroll
            for (int rr = 0; rr < 4; ++rr) {
                int row = m * 16 + kg * 4 + rr;
                int col = w * 32 + nt * 16 + l15;
                *(__bf16*)((char*)sF + row * 256 + ((col * 2) ^ ((row & 7) << 4))) = (__bf16)acc[m][nt][rr];
            }

    // ---- phi = f @ Wphi (kept in regs) ----
#pragma unroll
    for (int m = 0; m < 4; ++m) { accPhi[m][0] = f32x4v{0, 0, 0, 0}; accPhi[m][1] = f32x4v{0, 0, 0, 0}; }
    __syncthreads();                                 // prev sW reads + f writes
    stageW<32768, 256>(Wt + OFF_PHI, sW, t);
    __syncthreads();
    mfma_k128(sF, sW, w * 32, lane, accPhi);

    // ---- psi = f @ Wpsi -> bf16 global ----
#pragma unroll
    for (int m = 0; m < 4; ++m) { acc[m][0] = f32x4v{0, 0, 0, 0}; acc[m][1] = f32x4v{0, 0, 0, 0}; }
    __syncthreads();
    stageW<32768, 256>(Wt + OFF_PSI, sW, t);
    __syncthreads();
    mfma_k128(sF, sW, w * 32, lane, acc);
#pragma unroll
    for (int m = 0; m < 4; ++m)
#pragma unroll
        for (int nt = 0; nt < 2; ++nt)
#pragma unroll
            for (int rr = 0; rr < 4; ++rr) {
                int row = m * 16 + kg * 4 + rr;
                int col = w * 32 + nt * 16 + l15;
                psiB[(size_t)(p0 + row) * 128 + col] = f2b(acc[m][nt][rr]);
            }

    // ---- alpha = f @ Walpha -> bf16 global ----
#pragma unroll
    for (int m = 0; m < 4; ++m) { acc[m][0] = f32x4v{0, 0, 0, 0}; acc[m][1] = f32x4v{0, 0, 0, 0}; }
    __syncthreads();
    stageW<32768, 256>(Wt + OFF_ALF, sW, t);
    __syncthreads();
    mfma_k128(sF, sW, w * 32, lane, acc);
#pragma unroll
    for (int m = 0; m < 4; ++m)
#pragma unroll
        for (int nt = 0; nt < 2; ++nt)
#pragma unroll
            for (int rr = 0; rr < 4; ++rr) {
                int row = m * 16 + kg * 4 + rr;
                int col = w * 32 + nt * 16 + l15;
                alphaB[(size_t)(p0 + row) * 128 + col] = f2b(acc[m][nt][rr]);
            }

    // ---- t1 = relu(f @ Wdpt1 + b) ----
    {
        float bv0 = bdpt1[w * 32 + l15];
        float bv1 = bdpt1[w * 32 + 16 + l15];
#pragma unroll
        for (int m = 0; m < 4; ++m) { acc[m][0] = f32x4v{bv0, bv0, bv0, bv0}; acc[m][1] = f32x4v{bv1, bv1, bv1, bv1}; }
    }
    __syncthreads();
    stageW<32768, 256>(Wt + OFF_DPT1, sW, t);
    __syncthreads();
    mfma_k128(sF, sW, w * 32, lane, acc);
    __syncthreads();                                 // all f reads done
#pragma unroll
    for (int m = 0; m < 4; ++m)
#pragma unroll
        for (int nt = 0; nt < 2; ++nt)
#pragma unroll
            for (int rr = 0; rr < 4; ++rr) {
                int row = m * 16 + kg * 4 + rr;
                int col = w * 32 + nt * 16 + l15;
                *(__bf16*)((char*)sF + row * 256 + ((col * 2) ^ ((row & 7) << 4))) =
                    (__bf16)fmaxf(acc[m][nt][rr], 0.f);
            }

    // ---- base = phi + t1 @ Wdpt2 + b -> fp32 global ----
    {
        float bv0 = bdpt2[w * 32 + l15];
        float bv1 = bdpt2[w * 32 + 16 + l15];
#pragma unroll
        for (int m = 0; m < 4; ++m) { acc[m][0] = f32x4v{bv0, bv0, bv0, bv0}; acc[m][1] = f32x4v{bv1, bv1, bv1, bv1}; }
    }
    __syncthreads();                                 // prev sW reads + t1 writes
    stageW<32768, 256>(Wt + OFF_DPT2, sW, t);
    __syncthreads();
    mfma_k128(sF, sW, w * 32, lane, acc);
#pragma unroll
    for (int m = 0; m < 4; ++m)
#pragma unroll
        for (int nt = 0; nt < 2; ++nt)
#pragma unroll
            for (int rr = 0; rr < 4; ++rr) {
                int row = m * 16 + kg * 4 + rr;
                int col = w * 32 + nt * 16 + l15;
                base[(size_t)(p0 + row) * 128 + col] = acc[m][nt][rr] + accPhi[m][nt][rr];
            }
}

// ---------------------------------------------------------------------------
// Kernel 3 (MFMA): 4 points/block = 64 rows. Grid 4096 x 256 threads (4 waves).
// Full-weight (32 KB) staging per stage: 2 barriers/stage instead of 4.
// ---------------------------------------------------------------------------
__device__ __forceinline__ void do_stage(const u16* __restrict__ Wt_stage,
                                         const u16* sA, u16* sW,
                                         int t, int w, int lane,
                                         f32x4v (&acc)[4][2]) {
    __syncthreads();                                 // prev sW reads + pending sA writes
    stageW<32768, 256>(Wt_stage, sW, t);
    __syncthreads();                                 // sW + sA ready
    mfma_k128(sA, sW, w * 32, lane, acc);
}

__global__ __launch_bounds__(256, 2) void main_kernel(
    const float* __restrict__ x, const float* __restrict__ in_f,
    const float* __restrict__ Wdel1, const float* __restrict__ bdel1,
    const float* __restrict__ bdel2,
    const float* __restrict__ bgam1, const float* __restrict__ bgam2,
    const float* __restrict__ Wfc2, const float* __restrict__ bfc2,
    const float* __restrict__ base, const u16* __restrict__ psiB,
    const u16* __restrict__ alphaB, const int* __restrict__ knn,
    const u16* __restrict__ Wt, float* __restrict__ out) {
    __shared__ __align__(16) u16 sA[64 * 128];       // h1 -> pre -> g1 (swizzled)
    __shared__ __align__(16) u16 sBP[64 * 128];      // base-psi -> alpha (swizzled)
    __shared__ __align__(16) u16 sW[128 * 128];      // full-stage weight (32 KB)
    __shared__ float sWd1[512];                      // Wdel1 rows 0..2, bias at 384
    __shared__ float sDiff[64][3];
    __shared__ int sIdx[64];
    __shared__ float sY[4][128];

    const int t = threadIdx.x;
    const int lane = t & 63;
    const int w = t >> 6;
    const int kg = lane >> 4;
    const int l15 = lane & 15;
    const int p0 = blockIdx.x * 4;
    const int b = p0 >> 11;

    // ---- phase A ----
    if (t < 64) {
        int p = p0 + (t >> 4);
        int j = knn[p * Kq + (t & 15)];
        sIdx[t] = b * Nq + j;
        const float* xq = x + p * 3;
        const float* xn = x + ((size_t)(b * Nq + j)) * 3;
        sDiff[t][0] = xq[0] - xn[0];
        sDiff[t][1] = xq[1] - xn[1];
        sDiff[t][2] = xq[2] - xn[2];
    }
#pragma unroll
    for (int i = 0; i < 2; ++i) {
        int idx = t + i * 256;
        sWd1[idx] = (idx < 384) ? Wdel1[idx] : bdel1[idx - 384];
    }
    __syncthreads();

    // ---- phase B: h1 -> sA, base-psi -> sBP, alpha -> regs ----
    const int r = t >> 2;
    const int cb = t & 3;
    const float dx = sDiff[r][0], dy = sDiff[r][1], dz = sDiff[r][2];
    const int nrow = sIdx[r];
    const int prow = p0 + (r >> 4);
    bf16x8v aStash[4];
#pragma unroll
    for (int c8 = 0; c8 < 4; ++c8) {
        const int col0 = cb * 32 + c8 * 8;
        const int obyte = (col0 * 2) ^ ((r & 7) << 4);
        bf16x8v hv;
#pragma unroll
        for (int j = 0; j < 8; ++j) {
            int cc = col0 + j;
            float v = fmaf(dz, sWd1[256 + cc], fmaf(dy, sWd1[128 + cc], fmaf(dx, sWd1[cc], sWd1[384 + cc])));
            hv[j] = (__bf16)fmaxf(v, 0.f);
        }
        *(bf16x8v*)((char*)sA + r * 256 + obyte) = hv;
        bf16x8v ps = *(const bf16x8v*)&psiB[(size_t)nrow * 128 + col0];
        float4 b0 = *(const float4*)&base[(size_t)prow * 128 + col0];
        float4 b1 = *(const float4*)&base[(size_t)prow * 128 + col0 + 4];
        bf16x8v bp;
        bp[0] = (__bf16)(b0.x - (float)ps[0]); bp[1] = (__bf16)(b0.y - (float)ps[1]);
        bp[2] = (__bf16)(b0.z - (float)ps[2]); bp[3] = (__bf16)(b0.w - (float)ps[3]);
        bp[4] = (__bf16)(b1.x - (float)ps[4]); bp[5] = (__bf16)(b1.y - (float)ps[5]);
        bp[6] = (__bf16)(b1.z - (float)ps[6]); bp[7] = (__bf16)(b1.w - (float)ps[7]);
        *(bf16x8v*)((char*)sBP + r * 256 + obyte) = bp;
        aStash[c8] = *(const bf16x8v*)&alphaB[(size_t)nrow * 128 + col0];
    }

    // ---- del2: delta = h1 @ Wdel2 + b ----
    f32x4v accD[4][2], accW[4][2];
    {
        float bv0 = bdel2[w * 32 + l15];
        float bv1 = bdel2[w * 32 + 16 + l15];
#pragma unroll
        for (int m = 0; m < 4; ++m) { accD[m][0] = f32x4v{bv0, bv0, bv0, bv0}; accD[m][1] = f32x4v{bv1, bv1, bv1, bv1}; }
    }
    do_stage(Wt + OFF_DEL2, sA, sW, t, w, lane, accD);
    __syncthreads();                                 // all sA(h1) reads done

    // ---- pre = delta + bp -> sA ----
#pragma unroll
    for (int m = 0; m < 4; ++m)
#pragma unroll
        for (int nt = 0; nt < 2; ++nt)
#pragma unroll
            for (int rr = 0; rr < 4; ++rr) {
                int row = m * 16 + kg * 4 + rr;
                int col = w * 32 + nt * 16 + l15;
                int off = row * 256 + ((col * 2) ^ ((row & 7) << 4));
                float bp = (float)*(const __bf16*)((const char*)sBP + off);
                *(__bf16*)((char*)sA + off) = (__bf16)(accD[m][nt][rr] + bp);
            }
    __syncthreads();                                 // all bp reads done

    // ---- stash alpha into sBP ----
#pragma unroll
    for (int c8 = 0; c8 < 4; ++c8) {
        const int col0 = cb * 32 + c8 * 8;
        *(bf16x8v*)((char*)sBP + r * 256 + ((col0 * 2) ^ ((r & 7) << 4))) = aStash[c8];
    }

    // ---- gam1: g1 = relu(pre @ Wgam1 + b) ----
    {
        float bv0 = bgam1[w * 32 + l15];
        float bv1 = bgam1[w * 32 + 16 + l15];
#pragma unroll
        for (int m = 0; m < 4; ++m) { accW[m][0] = f32x4v{bv0, bv0, bv0, bv0}; accW[m][1] = f32x4v{bv1, bv1, bv1, bv1}; }
    }
    do_stage(Wt + OFF_GAM1, sA, sW, t, w, lane, accW);
    __syncthreads();                                 // all sA(pre) reads done

    // ---- g1 -> sA ----
#pragma unroll
    for (int m = 0; m < 4; ++m)
#pragma unroll
        for (int nt = 0; nt < 2; ++nt)
#pragma unroll
            for (int rr = 0; rr < 4; ++rr) {
                int row = m * 16 + kg * 4 + rr;
                int col = w * 32 + nt * 16 + l15;
                int off = row * 256 + ((col * 2) ^ ((row & 7) << 4));
                *(__bf16*)((char*)sA + off) = (__bf16)fmaxf(accW[m][nt][rr], 0.f);
            }

    // ---- gam2: gamma = g1 @ Wgam2 + b ----
    {
        float bv0 = bgam2[w * 32 + l15];
        float bv1 = bgam2[w * 32 + 16 + l15];
#pragma unroll
        for (int m = 0; m < 4; ++m) { accW[m][0] = f32x4v{bv0, bv0, bv0, bv0}; accW[m][1] = f32x4v{bv1, bv1, bv1, bv1}; }
    }
    do_stage(Wt + OFF_GAM2, sA, sW, t, w, lane, accW);  // leading barrier covers g1 writes

    // ---- softmax over k + y ----
#pragma unroll
    for (int m = 0; m < 4; ++m)
#pragma unroll
        for (int nt = 0; nt < 2; ++nt) {
            const int col = w * 32 + nt * 16 + l15;
            float g0 = accW[m][nt][0], g1v = accW[m][nt][1], g2 = accW[m][nt][2], g3 = accW[m][nt][3];
            float mx = fmaxf(fmaxf(g0, g1v), fmaxf(g2, g3));
            mx = fmaxf(mx, __shfl_xor(mx, 16, 64));
            mx = fmaxf(mx, __shfl_xor(mx, 32, 64));
            float m4 = mx * 0.25f;
            float e0 = expf(0.25f * g0 - m4), e1 = expf(0.25f * g1v - m4);
            float e2 = expf(0.25f * g2 - m4), e3 = expf(0.25f * g3 - m4);
            float s = e0 + e1 + e2 + e3;
            s += __shfl_xor(s, 16, 64);
            s += __shfl_xor(s, 32, 64);
            float y = 0.f;
#pragma unroll
            for (int rr = 0; rr < 4; ++rr) {
                int row = m * 16 + kg * 4 + rr;
                int off = row * 256 + ((col * 2) ^ ((row & 7) << 4));
                float al = (float)*(const __bf16*)((const char*)sBP + off);
                float ev = (rr == 0) ? e0 : (rr == 1) ? e1 : (rr == 2) ? e2 : e3;
                y = fmaf(ev, al + accD[m][nt][rr], y);
            }
            y += __shfl_xor(y, 16, 64);
            y += __shfl_xor(y, 32, 64);
            if (kg == 0) sY[m][col] = y / s;
        }
    __syncthreads();

    // ---- out = y @ Wfc2 + b + in_f ----
    {
        const int p = t >> 6;
        const int q = t & 63;
        const int gp = p0 + p;
        float a = bfc2[q] + in_f[(size_t)gp * 64 + q];
#pragma unroll 8
        for (int d = 0; d < 128; ++d)
            a = fmaf(sY[p][d], Wfc2[d * 64 + q], a);
        out[(size_t)gp * 64 + q] = a;
    }
}

// ---------------------------------------------------------------------------
extern "C" void kernel_launch(void* const* d_in, const int* in_sizes, int n_in,
                              void* d_out, int out_size, void* d_ws, size_t ws_size,
                              hipStream_t stream) {
    const float* x     = (const float*)d_in[0];
    const float* in_f  = (const float*)d_in[1];
    const float* Wfc1  = (const float*)d_in[2];
    const float* bfc1  = (const float*)d_in[3];
    const float* Wphi  = (const float*)d_in[4];
    const float* Wpsi  = (const float*)d_in[5];
    const float* Walpha= (const float*)d_in[6];
    const float* Wdpt1 = (const float*)d_in[7];
    const float* bdpt1 = (const float*)d_in[8];
    const float* Wdpt2 = (const float*)d_in[9];
    const float* bdpt2 = (const float*)d_in[10];
    const float* Wgam1 = (const float*)d_in[11];
    const float* bgam1 = (const float*)d_in[12];
    const float* Wgam2 = (const float*)d_in[13];
    const float* bgam2 = (const float*)d_in[14];
    const float* Wdel1 = (const float*)d_in[15];
    const float* bdel1 = (const float*)d_in[16];
    const float* Wdel2 = (const float*)d_in[17];
    const float* bdel2 = (const float*)d_in[18];
    const float* Wfc2  = (const float*)d_in[19];
    const float* bfc2  = (const float*)d_in[20];
    float* out = (float*)d_out;

    // ws: base f32 (8MB) | psiB bf16 (4MB) | alphaB bf16 (4MB) | knn (1MB) | Wt (272KB)
    float* base   = (float*)d_ws;
    u16*   psiB   = (u16*)(base + (size_t)BNq * Dq);
    u16*   alphaB = psiB + (size_t)BNq * Dq;
    int*   knn    = (int*)(alphaB + (size_t)BNq * Dq);
    u16*   Wt     = (u16*)(knn + (size_t)BNq * Kq);

    prep_kernel<<<WT_TOTAL / 256, 256, 0, stream>>>(Wdel2, Wgam1, Wgam2, Wfc1, Wphi,
                                                    Wpsi, Walpha, Wdpt1, Wdpt2, Wt);
    knn_kernel<<<512, 256, 0, stream>>>(x, knn);
    feat_kernel<<<BNq / 64, 256, 0, stream>>>(in_f, Wt, bfc1, bdpt1, bdpt2,
                                              base, psiB, alphaB);
    main_kernel<<<BNq / 4, 256, 0, stream>>>(x, in_f, Wdel1, bdel1, bdel2,
                                             bgam1, bgam2, Wfc2, bfc2,
                                             base, psiB, alphaB, knn, Wt, out);
}